// Round 5
// baseline (855.778 us; speedup 1.0000x reference)
//
#include <hip/hip_runtime.h>

// GCN layer: out = segment_sum(L_vals[:,None] * X[L_cols], L_rows) @ W^T + b
//
// Round-5: kill the CSR fine-sort (csr_scatter was 122us with 100MB WRITE_SIZE
// = 8x line amplification from random 8B stores). New pipeline:
//   1) ybuild: Y = X@W^T (named-float4 W in VGPRs, proven round 4)
//   2) bhist:  edge counts per 256-row bucket (NB=391), LDS-assisted
//   3) bscan:  1-block scan of 391 bucket counts -> bstart/cursor
//   4) bscatter: bin edges by bucket with per-bucket LDS line assembly --
//      flush groups of 8 int2 (=one 64B line) dense via bucket cursor.
//      Packed entry: key = (row&255)<<17 | col, val bits.
//   5) baggregate: one block per bucket, 64KB LDS acc[256][64]; dense edge
//      reads (unroll-8 -> 8 concurrent Y gathers), LDS f32 atomics, dense
//      out write with bias.
// Fallback to round-1 atomic path if ws_size too small.

constexpr int D  = 64;
constexpr int NN = 100000;   // nodes
constexpr int NE = 1600000;  // edges
constexpr int NB = (NN + 255) / 256;   // 391 buckets of 256 rows

// ws layout (bytes)
constexpr size_t WS_Y     = 0;                       // NN*D floats = 25.6 MB
constexpr size_t WS_BCNT  = 25600000;                // NB ints (pad 2048)
constexpr size_t WS_BSTRT = WS_BCNT  + 2048;         // NB+1 ints (pad 2048)
constexpr size_t WS_CURS  = WS_BSTRT + 2048;         // NB ints (pad 2048)
constexpr size_t WS_EDG   = WS_CURS  + 2048;         // NE int2 = 12.8 MB
constexpr size_t WS_NEED  = WS_EDG + 8ull * NE;      // ~38.4 MB

// ---------- 1) Y = X @ W^T (round-4, proven) ----------
__global__ __launch_bounds__(256) void gcn_ybuild(
    const float* __restrict__ X, const float* __restrict__ W,
    float* __restrict__ Y)
{
    __shared__ float xs[16][D];
    const int tid = threadIdx.x, wave = tid >> 6, lane = tid & 63;
    const int base = blockIdx.x * 16;

    ((float4*)xs)[tid] = ((const float4*)(X + base * D))[tid];

    const float4* W4 = (const float4*)W + lane * 16;
    const float4 w0 = W4[0],  w1 = W4[1],  w2 = W4[2],  w3 = W4[3];
    const float4 w4 = W4[4],  w5 = W4[5],  w6 = W4[6],  w7 = W4[7];
    const float4 w8 = W4[8],  w9 = W4[9],  w10 = W4[10], w11 = W4[11];
    const float4 w12 = W4[12], w13 = W4[13], w14 = W4[14], w15 = W4[15];

    __syncthreads();

    const int r = wave * 4;
    float a0 = 0.f, a1 = 0.f, a2 = 0.f, a3 = 0.f;

#define YB_STEP(k, wk)                                               \
    {                                                                \
        const float4 x0 = *(const float4*)&xs[r + 0][4 * (k)];       \
        const float4 x1 = *(const float4*)&xs[r + 1][4 * (k)];       \
        const float4 x2 = *(const float4*)&xs[r + 2][4 * (k)];       \
        const float4 x3 = *(const float4*)&xs[r + 3][4 * (k)];       \
        a0 = fmaf(x0.x, wk.x, a0); a0 = fmaf(x0.y, wk.y, a0);        \
        a0 = fmaf(x0.z, wk.z, a0); a0 = fmaf(x0.w, wk.w, a0);        \
        a1 = fmaf(x1.x, wk.x, a1); a1 = fmaf(x1.y, wk.y, a1);        \
        a1 = fmaf(x1.z, wk.z, a1); a1 = fmaf(x1.w, wk.w, a1);        \
        a2 = fmaf(x2.x, wk.x, a2); a2 = fmaf(x2.y, wk.y, a2);        \
        a2 = fmaf(x2.z, wk.z, a2); a2 = fmaf(x2.w, wk.w, a2);        \
        a3 = fmaf(x3.x, wk.x, a3); a3 = fmaf(x3.y, wk.y, a3);        \
        a3 = fmaf(x3.z, wk.z, a3); a3 = fmaf(x3.w, wk.w, a3);        \
    }
    YB_STEP(0, w0)   YB_STEP(1, w1)   YB_STEP(2, w2)   YB_STEP(3, w3)
    YB_STEP(4, w4)   YB_STEP(5, w5)   YB_STEP(6, w6)   YB_STEP(7, w7)
    YB_STEP(8, w8)   YB_STEP(9, w9)   YB_STEP(10, w10) YB_STEP(11, w11)
    YB_STEP(12, w12) YB_STEP(13, w13) YB_STEP(14, w14) YB_STEP(15, w15)
#undef YB_STEP

    float* yb = Y + (size_t)(base + r) * D + lane;
    yb[0 * D] = a0; yb[1 * D] = a1; yb[2 * D] = a2; yb[3 * D] = a3;
}

// ---------- 2) bucket histogram (LDS-assisted) ----------
__global__ __launch_bounds__(256) void gcn_bhist(
    const int* __restrict__ rows, int* __restrict__ bcnt)
{
    __shared__ int h[NB];
    const int tid = threadIdx.x;
    for (int i = tid; i < NB; i += 256) h[i] = 0;
    __syncthreads();
    for (int e = blockIdx.x * 256 + tid; e < NE; e += 256 * 256)
        atomicAdd(&h[rows[e] >> 8], 1);
    __syncthreads();
    for (int i = tid; i < NB; i += 256)
        if (h[i]) atomicAdd(&bcnt[i], h[i]);
}

// ---------- 3) scan of NB bucket counts (1 block, 512 thr) ----------
__global__ __launch_bounds__(512) void gcn_bscan(
    const int* __restrict__ bcnt, int* __restrict__ bstart,
    int* __restrict__ cursor)
{
    const int tid = threadIdx.x, lane = tid & 63, wid = tid >> 6;
    const int v = (tid < NB) ? bcnt[tid] : 0;
    int acc = v;
#pragma unroll
    for (int s = 1; s < 64; s <<= 1) {
        int t = __shfl_up(acc, s);
        if (lane >= s) acc += t;
    }
    __shared__ int wsum[8];
    if (lane == 63) wsum[wid] = acc;
    __syncthreads();
    if (wid == 0) {
        int wv = (lane < 8) ? wsum[lane] : 0;
#pragma unroll
        for (int s = 1; s < 8; s <<= 1) {
            int t = __shfl_up(wv, s);
            if (lane >= s) wv += t;
        }
        if (lane < 8) wsum[lane] = wv;
    }
    __syncthreads();
    if (wid > 0) acc += wsum[wid - 1];
    const int excl = acc - v;
    if (tid < NB) { bstart[tid] = excl; cursor[tid] = excl; }
    if (tid == NB - 1) bstart[NB] = acc;   // == NE
}

// ---------- 4) binned scatter with LDS line assembly ----------
// 128 blocks x 256 thr; each block owns 12500 consecutive edges, processed in
// rounds of 256. Full groups of 8 entries (64B) flush dense via cursor.
constexpr int SB_BLOCKS = 128;
constexpr int SB_EPB    = NE / SB_BLOCKS;   // 12500
constexpr int SB_CAP    = 16;
__global__ __launch_bounds__(256) void gcn_bscatter(
    const int* __restrict__ rows, const int* __restrict__ cols,
    const float* __restrict__ vals, int* __restrict__ cursor,
    int2* __restrict__ edges)
{
    __shared__ int2 buf[NB][SB_CAP];
    __shared__ int  cnt[NB];
    const int tid = threadIdx.x;
    const int base = blockIdx.x * SB_EPB;
    const int lim  = base + SB_EPB;

    for (int i = tid; i < NB; i += 256) cnt[i] = 0;
    __syncthreads();

    for (int e0 = base; e0 < lim; e0 += 256) {
        const int e = e0 + tid;
        if (e < lim) {
            const int r = rows[e];
            const int b = r >> 8;
            const int2 entry = make_int2(((r & 255) << 17) | cols[e],
                                         __float_as_int(vals[e]));
            const int slot = atomicAdd(&cnt[b], 1);
            if (slot < SB_CAP) {
                buf[b][slot] = entry;
            } else {
                // overflow (statistically ~never): direct scattered store
                const int pos = atomicAdd(&cursor[b], 1);
                edges[pos] = entry;
            }
        }
        __syncthreads();
        // flush full 8-groups (one 64B line each)
        for (int bb = tid; bb < NB; bb += 256) {
            int c = min(cnt[bb], SB_CAP);
            while (c >= 8) {
                const int pos = atomicAdd(&cursor[bb], 8);
#pragma unroll
                for (int k = 0; k < 8; ++k)
                    edges[pos + k] = buf[bb][c - 8 + k];
                c -= 8;
            }
            cnt[bb] = c;
        }
        __syncthreads();
    }
    // drain leftovers (<8 per bucket per block)
    for (int bb = tid; bb < NB; bb += 256) {
        const int c = min(cnt[bb], SB_CAP);
        if (c > 0) {
            const int pos = atomicAdd(&cursor[bb], c);
            for (int k = 0; k < c; ++k)
                edges[pos + k] = buf[bb][k];
        }
    }
}

// ---------- 5) bucket aggregate: LDS f32 accumulators ----------
// One block per bucket (391 blocks x 512 thr). acc[256][64] = 64KB LDS.
__global__ __launch_bounds__(512) void gcn_baggregate(
    const int* __restrict__ bstart, const int2* __restrict__ edges,
    const float* __restrict__ Y, const float* __restrict__ bias,
    float* __restrict__ out)
{
    __shared__ float acc[256 * D];
    const int tid = threadIdx.x, wave = tid >> 6, lane = tid & 63;
    const int b = blockIdx.x;

    for (int i = tid; i < 256 * D; i += 512) acc[i] = 0.f;
    __syncthreads();

    const int s   = bstart[b];
    const int cend = bstart[b + 1];
    const int cntb = cend - s;
    const int chunk = (cntb + 7) >> 3;
    const int js = s + wave * chunk;
    const int je = min(js + chunk, cend);

    int j = js;
    for (; j + 8 <= je; j += 8) {
        const int2 e0 = edges[j + 0], e1 = edges[j + 1];
        const int2 e2 = edges[j + 2], e3 = edges[j + 3];
        const int2 e4 = edges[j + 4], e5 = edges[j + 5];
        const int2 e6 = edges[j + 6], e7 = edges[j + 7];
        const float y0 = Y[(e0.x & 0x1FFFF) * D + lane];
        const float y1 = Y[(e1.x & 0x1FFFF) * D + lane];
        const float y2 = Y[(e2.x & 0x1FFFF) * D + lane];
        const float y3 = Y[(e3.x & 0x1FFFF) * D + lane];
        const float y4 = Y[(e4.x & 0x1FFFF) * D + lane];
        const float y5 = Y[(e5.x & 0x1FFFF) * D + lane];
        const float y6 = Y[(e6.x & 0x1FFFF) * D + lane];
        const float y7 = Y[(e7.x & 0x1FFFF) * D + lane];
        atomicAdd(&acc[(e0.x >> 17) * D + lane], __int_as_float(e0.y) * y0);
        atomicAdd(&acc[(e1.x >> 17) * D + lane], __int_as_float(e1.y) * y1);
        atomicAdd(&acc[(e2.x >> 17) * D + lane], __int_as_float(e2.y) * y2);
        atomicAdd(&acc[(e3.x >> 17) * D + lane], __int_as_float(e3.y) * y3);
        atomicAdd(&acc[(e4.x >> 17) * D + lane], __int_as_float(e4.y) * y4);
        atomicAdd(&acc[(e5.x >> 17) * D + lane], __int_as_float(e5.y) * y5);
        atomicAdd(&acc[(e6.x >> 17) * D + lane], __int_as_float(e6.y) * y6);
        atomicAdd(&acc[(e7.x >> 17) * D + lane], __int_as_float(e7.y) * y7);
    }
    for (; j < je; ++j) {
        const int2 e = edges[j];
        const float y = Y[(e.x & 0x1FFFF) * D + lane];
        atomicAdd(&acc[(e.x >> 17) * D + lane], __int_as_float(e.y) * y);
    }
    __syncthreads();

    const int rows0 = b * 256;
    const int nrows = min(256, NN - rows0);
    const float bl = bias[lane];
    for (int i = wave; i < nrows; i += 8)
        out[(size_t)(rows0 + i) * D + lane] = acc[i * D + lane] + bl;
}

// ---------- fallback (round-1 proven path) ----------
__global__ __launch_bounds__(256) void gcn_scatter_kernel(
    const int* __restrict__ rows, const int* __restrict__ cols,
    const float* __restrict__ vals, const float* __restrict__ X,
    float* __restrict__ agg)
{
    const int e    = blockIdx.x * 4 + (threadIdx.x >> 6);
    const int lane = threadIdx.x & 63;
    atomicAdd(&agg[rows[e] * D + lane], vals[e] * X[cols[e] * D + lane]);
}

__global__ __launch_bounds__(256) void gcn_transform_kernel(
    const float* __restrict__ W, const float* __restrict__ bias,
    float* __restrict__ out)
{
    __shared__ float Wl[D][D + 1];
    __shared__ float rowbuf[4][D];
    const int tid = threadIdx.x;
    for (int i = tid; i < D * D; i += 256)
        Wl[i >> 6][i & 63] = W[i];
    const int wave = tid >> 6, lane = tid & 63;
    const int n = blockIdx.x * 4 + wave;
    rowbuf[wave][lane] = out[n * D + lane];
    __syncthreads();
    float acc = bias[lane];
#pragma unroll
    for (int f = 0; f < D; ++f)
        acc += rowbuf[wave][f] * Wl[lane][f];
    out[n * D + lane] = acc;
}

extern "C" void kernel_launch(void* const* d_in, const int* in_sizes, int n_in,
                              void* d_out, int out_size, void* d_ws, size_t ws_size,
                              hipStream_t stream) {
    const int*   L_rows = (const int*)d_in[0];
    const int*   L_cols = (const int*)d_in[1];
    const float* L_vals = (const float*)d_in[2];
    const float* X      = (const float*)d_in[3];
    const float* W      = (const float*)d_in[4];
    const float* b      = (const float*)d_in[5];
    float* out = (float*)d_out;

    if (ws_size >= WS_NEED) {
        char* w = (char*)d_ws;
        float* Y      = (float*)(w + WS_Y);
        int*   bcnt   = (int*)  (w + WS_BCNT);
        int*   bstart = (int*)  (w + WS_BSTRT);
        int*   cursor = (int*)  (w + WS_CURS);
        int2*  edges  = (int2*) (w + WS_EDG);

        hipMemsetAsync(bcnt, 0, 2048, stream);

        gcn_ybuild<<<NN / 16, 256, 0, stream>>>(X, W, Y);
        gcn_bhist<<<256, 256, 0, stream>>>(L_rows, bcnt);
        gcn_bscan<<<1, 512, 0, stream>>>(bcnt, bstart, cursor);
        gcn_bscatter<<<SB_BLOCKS, 256, 0, stream>>>(L_rows, L_cols, L_vals,
                                                    cursor, edges);
        gcn_baggregate<<<NB, 512, 0, stream>>>(bstart, edges, Y, b, out);
    } else {
        hipMemsetAsync(out, 0, (size_t)out_size * sizeof(float), stream);
        gcn_scatter_kernel<<<NE / 4, 256, 0, stream>>>(L_rows, L_cols, L_vals, X, out);
        gcn_transform_kernel<<<NN / 4, 256, 0, stream>>>(W, b, out);
    }
}

// Round 6
// 223.555 us; speedup vs baseline: 3.8280x; 3.8280x over previous
//
#include <hip/hip_runtime.h>
#include <hip/hip_fp16.h>

// GCN layer: out = segment_sum(L_vals[:,None] * X[L_cols], L_rows) @ W^T + b
//
// Round-6 pipeline (lesson from r5: random-gather needs max occupancy; LDS
// accumulators that cap residency are net-negative):
//   1) ybuild:  Y = X@W^T, stored FP16 (halves gather bytes; |Y|<~6, quant
//               error ~0.02 << 0.3125 threshold)
//   2) bhist:   edge counts per 256-row bucket (NB=391)
//   3) bscan:   dual scan -> aligned bucket starts (8-entry = 64B aligned,
//               one writer per line) + compact starts for CSR
//   4) bscatter: bin edges to buckets with LDS 64B-line assembly (dense
//               aligned stores; kills round-4's 100MB write amplification)
//   5) bsort:   one block per bucket: LDS hist+scan+rescatter -> full CSR
//               order in EB + per-row offsets (random stores confined to a
//               32KB region per block -> L2-combined). Replaces the old
//               100K hist + 3-kernel scan entirely.
//   6) aggregate2: wave-per-row CSR gather, fp16 Y, unroll-8/4, 25000 blocks
//               (the proven high-MLP structure from rounds 2-4).
// Fallback to round-1 atomic path if ws_size too small.

constexpr int D  = 64;
constexpr int NN = 100000;   // nodes
constexpr int NE = 1600000;  // edges
constexpr int NB = (NN + 255) / 256;   // 391 buckets of 256 rows

// ws layout (bytes, 128-aligned)
constexpr size_t WS_YH   = 0;                    // NN*D halfs = 12.8 MB
constexpr size_t WS_EA   = 12800000;             // binned edges (aligned, padded)
constexpr size_t WS_EB   = WS_EA + 12822016;     // CSR edges = 12.8 MB
constexpr size_t WS_ROW  = WS_EB + 12800000;     // NN+1 ints
constexpr size_t WS_BCNT = WS_ROW + 400128;      // NB ints
constexpr size_t WS_AST  = WS_BCNT + 2048;       // NB ints (aligned starts)
constexpr size_t WS_CST  = WS_AST + 2048;        // NB+1 ints (compact starts)
constexpr size_t WS_CUR  = WS_CST + 2048;        // NB ints (scatter cursor)
constexpr size_t WS_NEED = WS_CUR + 2048;        // ~38.83 MB

// ---------- 1) Y = X @ W^T -> fp16 (named-float4 W in VGPRs, proven r4) ----
__global__ __launch_bounds__(256) void gcn_ybuild(
    const float* __restrict__ X, const float* __restrict__ W,
    __half* __restrict__ YH)
{
    __shared__ float xs[16][D];
    const int tid = threadIdx.x, wave = tid >> 6, lane = tid & 63;
    const int base = blockIdx.x * 16;

    ((float4*)xs)[tid] = ((const float4*)(X + base * D))[tid];

    const float4* W4 = (const float4*)W + lane * 16;
    const float4 w0 = W4[0],  w1 = W4[1],  w2 = W4[2],  w3 = W4[3];
    const float4 w4 = W4[4],  w5 = W4[5],  w6 = W4[6],  w7 = W4[7];
    const float4 w8 = W4[8],  w9 = W4[9],  w10 = W4[10], w11 = W4[11];
    const float4 w12 = W4[12], w13 = W4[13], w14 = W4[14], w15 = W4[15];

    __syncthreads();

    const int r = wave * 4;
    float a0 = 0.f, a1 = 0.f, a2 = 0.f, a3 = 0.f;

#define YB_STEP(k, wk)                                               \
    {                                                                \
        const float4 x0 = *(const float4*)&xs[r + 0][4 * (k)];       \
        const float4 x1 = *(const float4*)&xs[r + 1][4 * (k)];       \
        const float4 x2 = *(const float4*)&xs[r + 2][4 * (k)];       \
        const float4 x3 = *(const float4*)&xs[r + 3][4 * (k)];       \
        a0 = fmaf(x0.x, wk.x, a0); a0 = fmaf(x0.y, wk.y, a0);        \
        a0 = fmaf(x0.z, wk.z, a0); a0 = fmaf(x0.w, wk.w, a0);        \
        a1 = fmaf(x1.x, wk.x, a1); a1 = fmaf(x1.y, wk.y, a1);        \
        a1 = fmaf(x1.z, wk.z, a1); a1 = fmaf(x1.w, wk.w, a1);        \
        a2 = fmaf(x2.x, wk.x, a2); a2 = fmaf(x2.y, wk.y, a2);        \
        a2 = fmaf(x2.z, wk.z, a2); a2 = fmaf(x2.w, wk.w, a2);        \
        a3 = fmaf(x3.x, wk.x, a3); a3 = fmaf(x3.y, wk.y, a3);        \
        a3 = fmaf(x3.z, wk.z, a3); a3 = fmaf(x3.w, wk.w, a3);        \
    }
    YB_STEP(0, w0)   YB_STEP(1, w1)   YB_STEP(2, w2)   YB_STEP(3, w3)
    YB_STEP(4, w4)   YB_STEP(5, w5)   YB_STEP(6, w6)   YB_STEP(7, w7)
    YB_STEP(8, w8)   YB_STEP(9, w9)   YB_STEP(10, w10) YB_STEP(11, w11)
    YB_STEP(12, w12) YB_STEP(13, w13) YB_STEP(14, w14) YB_STEP(15, w15)
#undef YB_STEP

    __half* yb = YH + (size_t)(base + r) * D + lane;
    yb[0 * D] = __float2half(a0); yb[1 * D] = __float2half(a1);
    yb[2 * D] = __float2half(a2); yb[3 * D] = __float2half(a3);
}

// ---------- 2) bucket histogram (LDS-assisted) ----------
__global__ __launch_bounds__(256) void gcn_bhist(
    const int* __restrict__ rows, int* __restrict__ bcnt)
{
    __shared__ int h[NB];
    const int tid = threadIdx.x;
    for (int i = tid; i < NB; i += 256) h[i] = 0;
    __syncthreads();
    for (int e = blockIdx.x * 256 + tid; e < NE; e += 256 * 256)
        atomicAdd(&h[rows[e] >> 8], 1);
    __syncthreads();
    for (int i = tid; i < NB; i += 256)
        if (h[i]) atomicAdd(&bcnt[i], h[i]);
}

// ---------- 3) dual scan: aligned (8-entry) starts + compact starts --------
__global__ __launch_bounds__(512) void gcn_bscan(
    const int* __restrict__ bcnt, int* __restrict__ astart,
    int* __restrict__ cstart, int* __restrict__ cursor)
{
    const int tid = threadIdx.x, lane = tid & 63, wid = tid >> 6;
    const int v  = (tid < NB) ? bcnt[tid] : 0;
    const int vp = (v + 7) & ~7;
    int ac = v, ap = vp;
#pragma unroll
    for (int s = 1; s < 64; s <<= 1) {
        const int tc = __shfl_up(ac, s), tp = __shfl_up(ap, s);
        if (lane >= s) { ac += tc; ap += tp; }
    }
    __shared__ int wc[8], wp[8];
    if (lane == 63) { wc[wid] = ac; wp[wid] = ap; }
    __syncthreads();
    if (tid == 0) {
        int rc = 0, rp = 0;
        for (int k = 0; k < 8; ++k) {
            const int tc = wc[k], tp = wp[k];
            wc[k] = rc; wp[k] = rp; rc += tc; rp += tp;
        }
    }
    __syncthreads();
    ac += wc[wid]; ap += wp[wid];
    if (tid < NB) {
        astart[tid] = ap - vp;
        cursor[tid] = ap - vp;
        cstart[tid] = ac - v;
    }
    if (tid == NB - 1) cstart[NB] = ac;   // == NE
}

// ---------- 4) binned scatter with aligned LDS 64B-line assembly ----------
constexpr int SB_BLOCKS = 256;
constexpr int SB_EPB    = (NE + SB_BLOCKS - 1) / SB_BLOCKS;   // 6250
constexpr int SB_CAP    = 16;
__global__ __launch_bounds__(256) void gcn_bscatter(
    const int* __restrict__ rows, const int* __restrict__ cols,
    const float* __restrict__ vals, int* __restrict__ cursor,
    int2* __restrict__ EA)
{
    __shared__ int2 buf[NB][SB_CAP];
    __shared__ int  cnt[NB];
    const int tid = threadIdx.x;
    const int base = blockIdx.x * SB_EPB;
    const int lim  = min(base + SB_EPB, NE);

    for (int i = tid; i < NB; i += 256) cnt[i] = 0;
    __syncthreads();

    for (int e0 = base; e0 < lim; e0 += 256) {
        const int e = e0 + tid;
        if (e < lim) {
            const int r = rows[e];
            const int b = r >> 8;
            const int2 entry = make_int2(((r & 255) << 17) | cols[e],
                                         __float_as_int(vals[e]));
            const int slot = atomicAdd(&cnt[b], 1);
            if (slot < SB_CAP) {
                buf[b][slot] = entry;
            } else {
                const int pos = atomicAdd(&cursor[b], 1);   // rare overflow
                EA[pos] = entry;
            }
        }
        __syncthreads();
        for (int bb = tid; bb < NB; bb += 256) {
            int c = min(cnt[bb], SB_CAP);
            while (c >= 8) {                 // flush one 64B-aligned line
                const int pos = atomicAdd(&cursor[bb], 8);
#pragma unroll
                for (int k = 0; k < 8; ++k)
                    EA[pos + k] = buf[bb][c - 8 + k];
                c -= 8;
            }
            cnt[bb] = c;
        }
        __syncthreads();
    }
    for (int bb = tid; bb < NB; bb += 256) {
        const int c = min(cnt[bb], SB_CAP);
        if (c > 0) {
            const int pos = atomicAdd(&cursor[bb], c);
            for (int k = 0; k < c; ++k)
                EA[pos + k] = buf[bb][k];
        }
    }
}

// ---------- 5) per-bucket CSR sort + row offsets ----------
// One block per bucket; random stores confined to one 32KB region.
__global__ __launch_bounds__(256) void gcn_bsort(
    const int* __restrict__ astart, const int* __restrict__ cstart,
    const int2* __restrict__ EA, int2* __restrict__ EB,
    int* __restrict__ rowoff)
{
    __shared__ int hist[256], curs[256], sw[4];
    const int b = blockIdx.x, tid = threadIdx.x;
    const int s  = cstart[b];
    const int n  = cstart[b + 1] - s;
    const int a0 = astart[b];

    hist[tid] = 0;
    __syncthreads();
    for (int i = tid; i < n; i += 256)
        atomicAdd(&hist[EA[a0 + i].x >> 17], 1);
    __syncthreads();

    // exclusive scan of hist[256] (4 waves)
    const int lane = tid & 63, wid = tid >> 6;
    const int v = hist[tid];
    int acc = v;
#pragma unroll
    for (int st = 1; st < 64; st <<= 1) {
        const int t = __shfl_up(acc, st);
        if (lane >= st) acc += t;
    }
    if (lane == 63) sw[wid] = acc;
    __syncthreads();
    if (tid == 0) {
        int run = 0;
        for (int k = 0; k < 4; ++k) { const int t = sw[k]; sw[k] = run; run += t; }
    }
    __syncthreads();
    acc += sw[wid];
    const int excl = acc - v;
    curs[tid] = s + excl;

    const int rows0 = b * 256;
    if (rows0 + tid < NN) rowoff[rows0 + tid] = s + excl;
    if (b == NB - 1 && tid == 0) rowoff[NN] = NE;
    __syncthreads();

    for (int i = tid; i < n; i += 256) {
        const int2 E = EA[a0 + i];
        const int pos = atomicAdd(&curs[E.x >> 17], 1);
        EB[pos] = E;
    }
}

// ---------- 6) wave-per-row CSR aggregate, fp16 Y, unroll-8/4 ----------
__global__ __launch_bounds__(256) void gcn_aggregate2(
    const int* __restrict__ rowoff, const int2* __restrict__ EB,
    const __half* __restrict__ YH, const float* __restrict__ bias,
    float* __restrict__ out)
{
    const int wave = threadIdx.x >> 6, lane = threadIdx.x & 63;
    const int r = blockIdx.x * 4 + wave;            // NN % 4 == 0
    const int jstart = rowoff[r];
    const int jend   = rowoff[r + 1];
    float acc = bias[lane];
    int j = jstart;
    for (; j + 8 <= jend; j += 8) {
        const int2 e0 = EB[j + 0], e1 = EB[j + 1];
        const int2 e2 = EB[j + 2], e3 = EB[j + 3];
        const int2 e4 = EB[j + 4], e5 = EB[j + 5];
        const int2 e6 = EB[j + 6], e7 = EB[j + 7];
        const float y0 = __half2float(YH[(size_t)(e0.x & 0x1FFFF) * D + lane]);
        const float y1 = __half2float(YH[(size_t)(e1.x & 0x1FFFF) * D + lane]);
        const float y2 = __half2float(YH[(size_t)(e2.x & 0x1FFFF) * D + lane]);
        const float y3 = __half2float(YH[(size_t)(e3.x & 0x1FFFF) * D + lane]);
        const float y4 = __half2float(YH[(size_t)(e4.x & 0x1FFFF) * D + lane]);
        const float y5 = __half2float(YH[(size_t)(e5.x & 0x1FFFF) * D + lane]);
        const float y6 = __half2float(YH[(size_t)(e6.x & 0x1FFFF) * D + lane]);
        const float y7 = __half2float(YH[(size_t)(e7.x & 0x1FFFF) * D + lane]);
        acc = fmaf(__int_as_float(e0.y), y0, acc);
        acc = fmaf(__int_as_float(e1.y), y1, acc);
        acc = fmaf(__int_as_float(e2.y), y2, acc);
        acc = fmaf(__int_as_float(e3.y), y3, acc);
        acc = fmaf(__int_as_float(e4.y), y4, acc);
        acc = fmaf(__int_as_float(e5.y), y5, acc);
        acc = fmaf(__int_as_float(e6.y), y6, acc);
        acc = fmaf(__int_as_float(e7.y), y7, acc);
    }
    if (j + 4 <= jend) {
        const int2 e0 = EB[j + 0], e1 = EB[j + 1];
        const int2 e2 = EB[j + 2], e3 = EB[j + 3];
        const float y0 = __half2float(YH[(size_t)(e0.x & 0x1FFFF) * D + lane]);
        const float y1 = __half2float(YH[(size_t)(e1.x & 0x1FFFF) * D + lane]);
        const float y2 = __half2float(YH[(size_t)(e2.x & 0x1FFFF) * D + lane]);
        const float y3 = __half2float(YH[(size_t)(e3.x & 0x1FFFF) * D + lane]);
        acc = fmaf(__int_as_float(e0.y), y0, acc);
        acc = fmaf(__int_as_float(e1.y), y1, acc);
        acc = fmaf(__int_as_float(e2.y), y2, acc);
        acc = fmaf(__int_as_float(e3.y), y3, acc);
        j += 4;
    }
    for (; j < jend; ++j) {
        const int2 e = EB[j];
        acc = fmaf(__int_as_float(e.y),
                   __half2float(YH[(size_t)(e.x & 0x1FFFF) * D + lane]), acc);
    }
    out[(size_t)r * D + lane] = acc;
}

// ---------- fallback (round-1 proven path) ----------
__global__ __launch_bounds__(256) void gcn_scatter_kernel(
    const int* __restrict__ rows, const int* __restrict__ cols,
    const float* __restrict__ vals, const float* __restrict__ X,
    float* __restrict__ agg)
{
    const int e    = blockIdx.x * 4 + (threadIdx.x >> 6);
    const int lane = threadIdx.x & 63;
    atomicAdd(&agg[rows[e] * D + lane], vals[e] * X[cols[e] * D + lane]);
}

__global__ __launch_bounds__(256) void gcn_transform_kernel(
    const float* __restrict__ W, const float* __restrict__ bias,
    float* __restrict__ out)
{
    __shared__ float Wl[D][D + 1];
    __shared__ float rowbuf[4][D];
    const int tid = threadIdx.x;
    for (int i = tid; i < D * D; i += 256)
        Wl[i >> 6][i & 63] = W[i];
    const int wave = tid >> 6, lane = tid & 63;
    const int n = blockIdx.x * 4 + wave;
    rowbuf[wave][lane] = out[n * D + lane];
    __syncthreads();
    float acc = bias[lane];
#pragma unroll
    for (int f = 0; f < D; ++f)
        acc += rowbuf[wave][f] * Wl[lane][f];
    out[n * D + lane] = acc;
}

extern "C" void kernel_launch(void* const* d_in, const int* in_sizes, int n_in,
                              void* d_out, int out_size, void* d_ws, size_t ws_size,
                              hipStream_t stream) {
    const int*   L_rows = (const int*)d_in[0];
    const int*   L_cols = (const int*)d_in[1];
    const float* L_vals = (const float*)d_in[2];
    const float* X      = (const float*)d_in[3];
    const float* W      = (const float*)d_in[4];
    const float* b      = (const float*)d_in[5];
    float* out = (float*)d_out;

    if (ws_size >= WS_NEED) {
        char* w = (char*)d_ws;
        __half* YH     = (__half*)(w + WS_YH);
        int2*   EA     = (int2*)  (w + WS_EA);
        int2*   EB     = (int2*)  (w + WS_EB);
        int*    rowoff = (int*)   (w + WS_ROW);
        int*    bcnt   = (int*)   (w + WS_BCNT);
        int*    astart = (int*)   (w + WS_AST);
        int*    cstart = (int*)   (w + WS_CST);
        int*    cursor = (int*)   (w + WS_CUR);

        hipMemsetAsync(bcnt, 0, 2048, stream);

        gcn_ybuild<<<NN / 16, 256, 0, stream>>>(X, W, YH);
        gcn_bhist<<<256, 256, 0, stream>>>(L_rows, bcnt);
        gcn_bscan<<<1, 512, 0, stream>>>(bcnt, astart, cstart, cursor);
        gcn_bscatter<<<SB_BLOCKS, 256, 0, stream>>>(L_rows, L_cols, L_vals,
                                                    cursor, EA);
        gcn_bsort<<<NB, 256, 0, stream>>>(astart, cstart, EA, EB, rowoff);
        gcn_aggregate2<<<NN / 4, 256, 0, stream>>>(rowoff, EB, YH, b, out);
    } else {
        hipMemsetAsync(out, 0, (size_t)out_size * sizeof(float), stream);
        gcn_scatter_kernel<<<NE / 4, 256, 0, stream>>>(L_rows, L_cols, L_vals, X, out);
        gcn_transform_kernel<<<NN / 4, 256, 0, stream>>>(W, b, out);
    }
}

// Round 7
// 168.679 us; speedup vs baseline: 5.0734x; 1.3253x over previous
//
#include <hip/hip_runtime.h>
#include <hip/hip_fp16.h>

// GCN layer: out = segment_sum(L_vals[:,None] * X[L_cols], L_rows) @ W^T + b
//
// Round-7 pipeline (r6 lesson: LDS line-assembly scatter was serialization-
// bound at 9.5% occupancy / 87us; replaced with per-block counting-placement):
//   1) ybuild:    Y = X@W^T, stored FP16 (proven r6)
//   2) bhist:     global edge counts per 256-row bucket (NB=391)
//   3) bscan:     exclusive scan -> cstart (compact bucket starts) + cursor
//   4) place:     per-block: LDS hist(391) -> one global atomicAdd per bucket
//                 reserves a contiguous run in EA -> direct 8B stores into own
//                 run (L2-combined, ~1x write amplification, no round loop)
//   5) bsort:     one block per bucket: LDS hist+scan+rescatter -> row-sorted
//                 EB + per-row offsets (random stores confined to 32KB)
//   6) aggregate2: wave-per-row CSR gather, fp16 Y, unroll-8/4 (proven r6)
// Fallback to round-1 atomic path if ws_size too small.

constexpr int D  = 64;
constexpr int NN = 100000;   // nodes
constexpr int NE = 1600000;  // edges
constexpr int NB = (NN + 255) / 256;   // 391 buckets of 256 rows

// ws layout (bytes)
constexpr size_t WS_YH   = 0;                    // NN*D halfs = 12.8 MB
constexpr size_t WS_EA   = 12800000;             // NE int2 = 12.8 MB (compact)
constexpr size_t WS_EB   = 25600000;             // NE int2 = 12.8 MB (CSR)
constexpr size_t WS_ROW  = 38400000;             // NN+1 ints
constexpr size_t WS_BCNT = WS_ROW + 400128;      // NB ints
constexpr size_t WS_CST  = WS_BCNT + 2048;       // NB+1 ints
constexpr size_t WS_CUR  = WS_CST + 2048;        // NB ints
constexpr size_t WS_NEED = WS_CUR + 2048;        // ~38.81 MB

// ---------- 1) Y = X @ W^T -> fp16 (named-float4 W in VGPRs) ----------
__global__ __launch_bounds__(256) void gcn_ybuild(
    const float* __restrict__ X, const float* __restrict__ W,
    __half* __restrict__ YH)
{
    __shared__ float xs[16][D];
    const int tid = threadIdx.x, wave = tid >> 6, lane = tid & 63;
    const int base = blockIdx.x * 16;

    ((float4*)xs)[tid] = ((const float4*)(X + base * D))[tid];

    const float4* W4 = (const float4*)W + lane * 16;
    const float4 w0 = W4[0],  w1 = W4[1],  w2 = W4[2],  w3 = W4[3];
    const float4 w4 = W4[4],  w5 = W4[5],  w6 = W4[6],  w7 = W4[7];
    const float4 w8 = W4[8],  w9 = W4[9],  w10 = W4[10], w11 = W4[11];
    const float4 w12 = W4[12], w13 = W4[13], w14 = W4[14], w15 = W4[15];

    __syncthreads();

    const int r = wave * 4;
    float a0 = 0.f, a1 = 0.f, a2 = 0.f, a3 = 0.f;

#define YB_STEP(k, wk)                                               \
    {                                                                \
        const float4 x0 = *(const float4*)&xs[r + 0][4 * (k)];       \
        const float4 x1 = *(const float4*)&xs[r + 1][4 * (k)];       \
        const float4 x2 = *(const float4*)&xs[r + 2][4 * (k)];       \
        const float4 x3 = *(const float4*)&xs[r + 3][4 * (k)];       \
        a0 = fmaf(x0.x, wk.x, a0); a0 = fmaf(x0.y, wk.y, a0);        \
        a0 = fmaf(x0.z, wk.z, a0); a0 = fmaf(x0.w, wk.w, a0);        \
        a1 = fmaf(x1.x, wk.x, a1); a1 = fmaf(x1.y, wk.y, a1);        \
        a1 = fmaf(x1.z, wk.z, a1); a1 = fmaf(x1.w, wk.w, a1);        \
        a2 = fmaf(x2.x, wk.x, a2); a2 = fmaf(x2.y, wk.y, a2);        \
        a2 = fmaf(x2.z, wk.z, a2); a2 = fmaf(x2.w, wk.w, a2);        \
        a3 = fmaf(x3.x, wk.x, a3); a3 = fmaf(x3.y, wk.y, a3);        \
        a3 = fmaf(x3.z, wk.z, a3); a3 = fmaf(x3.w, wk.w, a3);        \
    }
    YB_STEP(0, w0)   YB_STEP(1, w1)   YB_STEP(2, w2)   YB_STEP(3, w3)
    YB_STEP(4, w4)   YB_STEP(5, w5)   YB_STEP(6, w6)   YB_STEP(7, w7)
    YB_STEP(8, w8)   YB_STEP(9, w9)   YB_STEP(10, w10) YB_STEP(11, w11)
    YB_STEP(12, w12) YB_STEP(13, w13) YB_STEP(14, w14) YB_STEP(15, w15)
#undef YB_STEP

    __half* yb = YH + (size_t)(base + r) * D + lane;
    yb[0 * D] = __float2half(a0); yb[1 * D] = __float2half(a1);
    yb[2 * D] = __float2half(a2); yb[3 * D] = __float2half(a3);
}

// ---------- 2) bucket histogram (LDS-assisted) ----------
__global__ __launch_bounds__(256) void gcn_bhist(
    const int* __restrict__ rows, int* __restrict__ bcnt)
{
    __shared__ int h[NB];
    const int tid = threadIdx.x;
    for (int i = tid; i < NB; i += 256) h[i] = 0;
    __syncthreads();
    for (int e = blockIdx.x * 256 + tid; e < NE; e += 256 * 256)
        atomicAdd(&h[rows[e] >> 8], 1);
    __syncthreads();
    for (int i = tid; i < NB; i += 256)
        if (h[i]) atomicAdd(&bcnt[i], h[i]);
}

// ---------- 3) exclusive scan of NB bucket counts -> cstart, cursor --------
__global__ __launch_bounds__(512) void gcn_bscan(
    const int* __restrict__ bcnt, int* __restrict__ cstart,
    int* __restrict__ cursor)
{
    const int tid = threadIdx.x, lane = tid & 63, wid = tid >> 6;
    const int v = (tid < NB) ? bcnt[tid] : 0;
    int acc = v;
#pragma unroll
    for (int s = 1; s < 64; s <<= 1) {
        const int t = __shfl_up(acc, s);
        if (lane >= s) acc += t;
    }
    __shared__ int wsum[8];
    if (lane == 63) wsum[wid] = acc;
    __syncthreads();
    if (tid == 0) {
        int run = 0;
        for (int k = 0; k < 8; ++k) { const int t = wsum[k]; wsum[k] = run; run += t; }
    }
    __syncthreads();
    acc += wsum[wid];
    const int excl = acc - v;
    if (tid < NB) { cstart[tid] = excl; cursor[tid] = excl; }
    if (tid == NB - 1) cstart[NB] = acc;   // == NE
}

// ---------- 4) counting placement into per-bucket runs ----------
// 256 blocks x 256 thr; block owns 6250 consecutive edges. One global atomic
// per (block,bucket) reserves a contiguous EA run; 8B stores land in own run.
constexpr int PL_BLOCKS = 256;
constexpr int PL_EPB    = NE / PL_BLOCKS;   // 6250
__global__ __launch_bounds__(256) void gcn_place(
    const int* __restrict__ rows, const int* __restrict__ cols,
    const float* __restrict__ vals, int* __restrict__ cursor,
    int2* __restrict__ EA)
{
    __shared__ int hist[NB];    // pass1: local counts; pass2: local rank cursor
    __shared__ int rbase[NB];   // reserved global run start per bucket
    const int tid = threadIdx.x;
    const int base = blockIdx.x * PL_EPB;

    for (int i = tid; i < NB; i += 256) hist[i] = 0;
    __syncthreads();
    for (int i = tid; i < PL_EPB; i += 256)
        atomicAdd(&hist[rows[base + i] >> 8], 1);
    __syncthreads();
    for (int i = tid; i < NB; i += 256) {
        const int c = hist[i];
        rbase[i] = c ? atomicAdd(&cursor[i], c) : 0;
    }
    __syncthreads();
    for (int i = tid; i < NB; i += 256) hist[i] = 0;   // reuse as local cursor
    __syncthreads();
    for (int i = tid; i < PL_EPB; i += 256) {
        const int e = base + i;
        const int r = rows[e];                          // L2-hot re-read
        const int b = r >> 8;
        const int rank = atomicAdd(&hist[b], 1);
        EA[rbase[b] + rank] = make_int2(((r & 255) << 17) | cols[e],
                                        __float_as_int(vals[e]));
    }
}

// ---------- 5) per-bucket CSR sort + row offsets ----------
__global__ __launch_bounds__(256) void gcn_bsort(
    const int* __restrict__ cstart, const int2* __restrict__ EA,
    int2* __restrict__ EB, int* __restrict__ rowoff)
{
    __shared__ int hist[256], curs[256], sw[4];
    const int b = blockIdx.x, tid = threadIdx.x;
    const int s = cstart[b];
    const int n = cstart[b + 1] - s;

    hist[tid] = 0;
    __syncthreads();
    for (int i = tid; i < n; i += 256)
        atomicAdd(&hist[EA[s + i].x >> 17], 1);
    __syncthreads();

    const int lane = tid & 63, wid = tid >> 6;
    const int v = hist[tid];
    int acc = v;
#pragma unroll
    for (int st = 1; st < 64; st <<= 1) {
        const int t = __shfl_up(acc, st);
        if (lane >= st) acc += t;
    }
    if (lane == 63) sw[wid] = acc;
    __syncthreads();
    if (tid == 0) {
        int run = 0;
        for (int k = 0; k < 4; ++k) { const int t = sw[k]; sw[k] = run; run += t; }
    }
    __syncthreads();
    acc += sw[wid];
    const int excl = acc - v;
    curs[tid] = s + excl;

    const int rows0 = b * 256;
    if (rows0 + tid < NN) rowoff[rows0 + tid] = s + excl;
    if (b == NB - 1 && tid == 0) rowoff[NN] = NE;
    __syncthreads();

    for (int i = tid; i < n; i += 256) {
        const int2 E = EA[s + i];
        const int pos = atomicAdd(&curs[E.x >> 17], 1);
        EB[pos] = E;
    }
}

// ---------- 6) wave-per-row CSR aggregate, fp16 Y, unroll-8/4 ----------
__global__ __launch_bounds__(256) void gcn_aggregate2(
    const int* __restrict__ rowoff, const int2* __restrict__ EB,
    const __half* __restrict__ YH, const float* __restrict__ bias,
    float* __restrict__ out)
{
    const int wave = threadIdx.x >> 6, lane = threadIdx.x & 63;
    const int r = blockIdx.x * 4 + wave;            // NN % 4 == 0
    const int jstart = rowoff[r];
    const int jend   = rowoff[r + 1];
    float acc = bias[lane];
    int j = jstart;
    for (; j + 8 <= jend; j += 8) {
        const int2 e0 = EB[j + 0], e1 = EB[j + 1];
        const int2 e2 = EB[j + 2], e3 = EB[j + 3];
        const int2 e4 = EB[j + 4], e5 = EB[j + 5];
        const int2 e6 = EB[j + 6], e7 = EB[j + 7];
        const float y0 = __half2float(YH[(size_t)(e0.x & 0x1FFFF) * D + lane]);
        const float y1 = __half2float(YH[(size_t)(e1.x & 0x1FFFF) * D + lane]);
        const float y2 = __half2float(YH[(size_t)(e2.x & 0x1FFFF) * D + lane]);
        const float y3 = __half2float(YH[(size_t)(e3.x & 0x1FFFF) * D + lane]);
        const float y4 = __half2float(YH[(size_t)(e4.x & 0x1FFFF) * D + lane]);
        const float y5 = __half2float(YH[(size_t)(e5.x & 0x1FFFF) * D + lane]);
        const float y6 = __half2float(YH[(size_t)(e6.x & 0x1FFFF) * D + lane]);
        const float y7 = __half2float(YH[(size_t)(e7.x & 0x1FFFF) * D + lane]);
        acc = fmaf(__int_as_float(e0.y), y0, acc);
        acc = fmaf(__int_as_float(e1.y), y1, acc);
        acc = fmaf(__int_as_float(e2.y), y2, acc);
        acc = fmaf(__int_as_float(e3.y), y3, acc);
        acc = fmaf(__int_as_float(e4.y), y4, acc);
        acc = fmaf(__int_as_float(e5.y), y5, acc);
        acc = fmaf(__int_as_float(e6.y), y6, acc);
        acc = fmaf(__int_as_float(e7.y), y7, acc);
    }
    if (j + 4 <= jend) {
        const int2 e0 = EB[j + 0], e1 = EB[j + 1];
        const int2 e2 = EB[j + 2], e3 = EB[j + 3];
        const float y0 = __half2float(YH[(size_t)(e0.x & 0x1FFFF) * D + lane]);
        const float y1 = __half2float(YH[(size_t)(e1.x & 0x1FFFF) * D + lane]);
        const float y2 = __half2float(YH[(size_t)(e2.x & 0x1FFFF) * D + lane]);
        const float y3 = __half2float(YH[(size_t)(e3.x & 0x1FFFF) * D + lane]);
        acc = fmaf(__int_as_float(e0.y), y0, acc);
        acc = fmaf(__int_as_float(e1.y), y1, acc);
        acc = fmaf(__int_as_float(e2.y), y2, acc);
        acc = fmaf(__int_as_float(e3.y), y3, acc);
        j += 4;
    }
    for (; j < jend; ++j) {
        const int2 e = EB[j];
        acc = fmaf(__int_as_float(e.y),
                   __half2float(YH[(size_t)(e.x & 0x1FFFF) * D + lane]), acc);
    }
    out[(size_t)r * D + lane] = acc;
}

// ---------- fallback (round-1 proven path) ----------
__global__ __launch_bounds__(256) void gcn_scatter_kernel(
    const int* __restrict__ rows, const int* __restrict__ cols,
    const float* __restrict__ vals, const float* __restrict__ X,
    float* __restrict__ agg)
{
    const int e    = blockIdx.x * 4 + (threadIdx.x >> 6);
    const int lane = threadIdx.x & 63;
    atomicAdd(&agg[rows[e] * D + lane], vals[e] * X[cols[e] * D + lane]);
}

__global__ __launch_bounds__(256) void gcn_transform_kernel(
    const float* __restrict__ W, const float* __restrict__ bias,
    float* __restrict__ out)
{
    __shared__ float Wl[D][D + 1];
    __shared__ float rowbuf[4][D];
    const int tid = threadIdx.x;
    for (int i = tid; i < D * D; i += 256)
        Wl[i >> 6][i & 63] = W[i];
    const int wave = tid >> 6, lane = tid & 63;
    const int n = blockIdx.x * 4 + wave;
    rowbuf[wave][lane] = out[n * D + lane];
    __syncthreads();
    float acc = bias[lane];
#pragma unroll
    for (int f = 0; f < D; ++f)
        acc += rowbuf[wave][f] * Wl[lane][f];
    out[n * D + lane] = acc;
}

extern "C" void kernel_launch(void* const* d_in, const int* in_sizes, int n_in,
                              void* d_out, int out_size, void* d_ws, size_t ws_size,
                              hipStream_t stream) {
    const int*   L_rows = (const int*)d_in[0];
    const int*   L_cols = (const int*)d_in[1];
    const float* L_vals = (const float*)d_in[2];
    const float* X      = (const float*)d_in[3];
    const float* W      = (const float*)d_in[4];
    const float* b      = (const float*)d_in[5];
    float* out = (float*)d_out;

    if (ws_size >= WS_NEED) {
        char* w = (char*)d_ws;
        __half* YH     = (__half*)(w + WS_YH);
        int2*   EA     = (int2*)  (w + WS_EA);
        int2*   EB     = (int2*)  (w + WS_EB);
        int*    rowoff = (int*)   (w + WS_ROW);
        int*    bcnt   = (int*)   (w + WS_BCNT);
        int*    cstart = (int*)   (w + WS_CST);
        int*    cursor = (int*)   (w + WS_CUR);

        hipMemsetAsync(bcnt, 0, 2048, stream);

        gcn_ybuild<<<NN / 16, 256, 0, stream>>>(X, W, YH);
        gcn_bhist<<<256, 256, 0, stream>>>(L_rows, bcnt);
        gcn_bscan<<<1, 512, 0, stream>>>(bcnt, cstart, cursor);
        gcn_place<<<PL_BLOCKS, 256, 0, stream>>>(L_rows, L_cols, L_vals,
                                                 cursor, EA);
        gcn_bsort<<<NB, 256, 0, stream>>>(cstart, EA, EB, rowoff);
        gcn_aggregate2<<<NN / 4, 256, 0, stream>>>(rowoff, EB, YH, b, out);
    } else {
        hipMemsetAsync(out, 0, (size_t)out_size * sizeof(float), stream);
        gcn_scatter_kernel<<<NE / 4, 256, 0, stream>>>(L_rows, L_cols, L_vals, X, out);
        gcn_transform_kernel<<<NN / 4, 256, 0, stream>>>(W, b, out);
    }
}

// Round 8
// 145.685 us; speedup vs baseline: 5.8742x; 1.1578x over previous
//
#include <hip/hip_runtime.h>
#include <hip/hip_fp16.h>

// GCN layer: out = segment_sum(L_vals[:,None] * X[L_cols], L_rows) @ W^T + b
//
// Round-8 pipeline (r7 lesson: aggregate's random-gather is near its L2/L3
// floor at 55us; the fat is preprocessing). bsort is FUSED into the
// aggregate: each block takes a HALF-bucket (128 rows), row-sorts its edges
// in LDS (hist+scan+reorder, 22KB), then aggregates from LDS directly.
// Deletes bsort dispatch + EB (12.8MB write + 12.8MB read) + rowoff.
//   1) ybuild:    Y = X@W^T, stored FP16 (proven)
//   2) bhist:     edge counts per 256-row bucket (NB=391)
//   3) bscan:     exclusive scan -> cstart + cursor
//   4) place:     per-block counting placement into per-bucket EA runs (proven)
//   5) bucketagg: 782 blocks x 512 thr; in-LDS row-sort of half-bucket +
//                 wave-per-row unroll-8 fp16-Y gather aggregate
// Fallback to round-1 atomic path if ws_size too small.

constexpr int D  = 64;
constexpr int NN = 100000;   // nodes
constexpr int NE = 1600000;  // edges
constexpr int NB = (NN + 255) / 256;   // 391 buckets of 256 rows

// ws layout (bytes)
constexpr size_t WS_YH   = 0;                    // NN*D halfs = 12.8 MB
constexpr size_t WS_EA   = 12800000;             // NE int2 = 12.8 MB
constexpr size_t WS_BCNT = 25600000;             // NB ints
constexpr size_t WS_CST  = WS_BCNT + 2048;       // NB+1 ints
constexpr size_t WS_CUR  = WS_CST + 2048;        // NB ints
constexpr size_t WS_NEED = WS_CUR + 2048;        // ~25.6 MB

// ---------- 1) Y = X @ W^T -> fp16 (named-float4 W in VGPRs) ----------
__global__ __launch_bounds__(256) void gcn_ybuild(
    const float* __restrict__ X, const float* __restrict__ W,
    __half* __restrict__ YH)
{
    __shared__ float xs[16][D];
    const int tid = threadIdx.x, wave = tid >> 6, lane = tid & 63;
    const int base = blockIdx.x * 16;

    ((float4*)xs)[tid] = ((const float4*)(X + base * D))[tid];

    const float4* W4 = (const float4*)W + lane * 16;
    const float4 w0 = W4[0],  w1 = W4[1],  w2 = W4[2],  w3 = W4[3];
    const float4 w4 = W4[4],  w5 = W4[5],  w6 = W4[6],  w7 = W4[7];
    const float4 w8 = W4[8],  w9 = W4[9],  w10 = W4[10], w11 = W4[11];
    const float4 w12 = W4[12], w13 = W4[13], w14 = W4[14], w15 = W4[15];

    __syncthreads();

    const int r = wave * 4;
    float a0 = 0.f, a1 = 0.f, a2 = 0.f, a3 = 0.f;

#define YB_STEP(k, wk)                                               \
    {                                                                \
        const float4 x0 = *(const float4*)&xs[r + 0][4 * (k)];       \
        const float4 x1 = *(const float4*)&xs[r + 1][4 * (k)];       \
        const float4 x2 = *(const float4*)&xs[r + 2][4 * (k)];       \
        const float4 x3 = *(const float4*)&xs[r + 3][4 * (k)];       \
        a0 = fmaf(x0.x, wk.x, a0); a0 = fmaf(x0.y, wk.y, a0);        \
        a0 = fmaf(x0.z, wk.z, a0); a0 = fmaf(x0.w, wk.w, a0);        \
        a1 = fmaf(x1.x, wk.x, a1); a1 = fmaf(x1.y, wk.y, a1);        \
        a1 = fmaf(x1.z, wk.z, a1); a1 = fmaf(x1.w, wk.w, a1);        \
        a2 = fmaf(x2.x, wk.x, a2); a2 = fmaf(x2.y, wk.y, a2);        \
        a2 = fmaf(x2.z, wk.z, a2); a2 = fmaf(x2.w, wk.w, a2);        \
        a3 = fmaf(x3.x, wk.x, a3); a3 = fmaf(x3.y, wk.y, a3);        \
        a3 = fmaf(x3.z, wk.z, a3); a3 = fmaf(x3.w, wk.w, a3);        \
    }
    YB_STEP(0, w0)   YB_STEP(1, w1)   YB_STEP(2, w2)   YB_STEP(3, w3)
    YB_STEP(4, w4)   YB_STEP(5, w5)   YB_STEP(6, w6)   YB_STEP(7, w7)
    YB_STEP(8, w8)   YB_STEP(9, w9)   YB_STEP(10, w10) YB_STEP(11, w11)
    YB_STEP(12, w12) YB_STEP(13, w13) YB_STEP(14, w14) YB_STEP(15, w15)
#undef YB_STEP

    __half* yb = YH + (size_t)(base + r) * D + lane;
    yb[0 * D] = __float2half(a0); yb[1 * D] = __float2half(a1);
    yb[2 * D] = __float2half(a2); yb[3 * D] = __float2half(a3);
}

// ---------- 2) bucket histogram (LDS-assisted) ----------
__global__ __launch_bounds__(256) void gcn_bhist(
    const int* __restrict__ rows, int* __restrict__ bcnt)
{
    __shared__ int h[NB];
    const int tid = threadIdx.x;
    for (int i = tid; i < NB; i += 256) h[i] = 0;
    __syncthreads();
    for (int e = blockIdx.x * 256 + tid; e < NE; e += 256 * 256)
        atomicAdd(&h[rows[e] >> 8], 1);
    __syncthreads();
    for (int i = tid; i < NB; i += 256)
        if (h[i]) atomicAdd(&bcnt[i], h[i]);
}

// ---------- 3) exclusive scan of NB bucket counts -> cstart, cursor --------
__global__ __launch_bounds__(512) void gcn_bscan(
    const int* __restrict__ bcnt, int* __restrict__ cstart,
    int* __restrict__ cursor)
{
    const int tid = threadIdx.x, lane = tid & 63, wid = tid >> 6;
    const int v = (tid < NB) ? bcnt[tid] : 0;
    int acc = v;
#pragma unroll
    for (int s = 1; s < 64; s <<= 1) {
        const int t = __shfl_up(acc, s);
        if (lane >= s) acc += t;
    }
    __shared__ int wsum[8];
    if (lane == 63) wsum[wid] = acc;
    __syncthreads();
    if (tid == 0) {
        int run = 0;
        for (int k = 0; k < 8; ++k) { const int t = wsum[k]; wsum[k] = run; run += t; }
    }
    __syncthreads();
    acc += wsum[wid];
    const int excl = acc - v;
    if (tid < NB) { cstart[tid] = excl; cursor[tid] = excl; }
    if (tid == NB - 1) cstart[NB] = acc;   // == NE
}

// ---------- 4) counting placement into per-bucket runs (proven r7) --------
constexpr int PL_BLOCKS = 256;
constexpr int PL_EPB    = NE / PL_BLOCKS;   // 6250
__global__ __launch_bounds__(256) void gcn_place(
    const int* __restrict__ rows, const int* __restrict__ cols,
    const float* __restrict__ vals, int* __restrict__ cursor,
    int2* __restrict__ EA)
{
    __shared__ int hist[NB];
    __shared__ int rbase[NB];
    const int tid = threadIdx.x;
    const int base = blockIdx.x * PL_EPB;

    for (int i = tid; i < NB; i += 256) hist[i] = 0;
    __syncthreads();
    for (int i = tid; i < PL_EPB; i += 256)
        atomicAdd(&hist[rows[base + i] >> 8], 1);
    __syncthreads();
    for (int i = tid; i < NB; i += 256) {
        const int c = hist[i];
        rbase[i] = c ? atomicAdd(&cursor[i], c) : 0;
    }
    __syncthreads();
    for (int i = tid; i < NB; i += 256) hist[i] = 0;
    __syncthreads();
    for (int i = tid; i < PL_EPB; i += 256) {
        const int e = base + i;
        const int r = rows[e];
        const int b = r >> 8;
        const int rank = atomicAdd(&hist[b], 1);
        EA[rbase[b] + rank] = make_int2(((r & 255) << 17) | cols[e],
                                        __float_as_int(vals[e]));
    }
}

// ---------- 5) fused in-LDS row-sort + aggregate (half-bucket/block) -------
// Block bb: bucket b=bb>>1, half=bb&1 -> rows [b*256+half*128, +128).
// Reads the whole bucket's EA segment twice (hist pass + place pass), sorts
// OWN half's edges into sbuf, then wave-per-row unroll-8 gather aggregate.
constexpr int HCAP = 2560;   // half-bucket capacity: mean 2046, +11 sigma
__global__ __launch_bounds__(512) void gcn_bucketagg(
    const int* __restrict__ cstart, const int2* __restrict__ EA,
    const __half* __restrict__ YH, const float* __restrict__ bias,
    float* __restrict__ out)
{
    __shared__ int2 sbuf[HCAP];
    __shared__ int hist[128], start[128], curs[128];
    __shared__ int sw1;
    const int tid = threadIdx.x;
    const int bb = blockIdx.x, b = bb >> 1, half = bb & 1;
    const int s = cstart[b], n = cstart[b + 1] - s;

    if (tid < 128) hist[tid] = 0;
    __syncthreads();

    // pass 1: histogram own half's rows
    for (int i = tid; i < n; i += 512) {
        const int rr = EA[s + i].x >> 17;          // row-in-bucket 0..255
        if ((rr >> 7) == half) atomicAdd(&hist[rr & 127], 1);
    }
    __syncthreads();

    // exclusive scan of hist[128] (waves 0-1 active; no divergent barriers)
    int v = 0, acc = 0;
    if (tid < 128) {
        v = hist[tid];
        acc = v;
        const int lane = tid & 63;
#pragma unroll
        for (int st = 1; st < 64; st <<= 1) {
            const int t = __shfl_up(acc, st);
            if (lane >= st) acc += t;
        }
    }
    if (tid == 63) sw1 = acc;
    __syncthreads();
    if (tid >= 64 && tid < 128) acc += sw1;
    if (tid < 128) {
        start[tid] = acc - v;
        curs[tid]  = acc - v;
    }
    __syncthreads();

    // pass 2: place own half's edges into sbuf (row-sorted)
    for (int i = tid; i < n; i += 512) {
        const int2 E = EA[s + i];
        const int rr = E.x >> 17;
        if ((rr >> 7) == half) {
            const int pos = atomicAdd(&curs[rr & 127], 1);
            if (pos < HCAP) sbuf[pos] = make_int2(E.x & 0x1FFFF, E.y);
        }
    }
    __syncthreads();

    // pass 3: wave-per-row aggregate, 16 rows per wave, unroll-8/4
    const int wv = tid >> 6, lane = tid & 63;
    const float bl = bias[lane];
    const int rows0 = b * 256 + half * 128;
#pragma unroll 1
    for (int k = 0; k < 16; ++k) {
        const int lr = wv * 16 + k;
        const int js = start[lr];
        const int je = js + hist[lr];
        float acc2 = bl;
        int j = js;
        for (; j + 8 <= je; j += 8) {
            const int2 e0 = sbuf[j + 0], e1 = sbuf[j + 1];
            const int2 e2 = sbuf[j + 2], e3 = sbuf[j + 3];
            const int2 e4 = sbuf[j + 4], e5 = sbuf[j + 5];
            const int2 e6 = sbuf[j + 6], e7 = sbuf[j + 7];
            const float y0 = __half2float(YH[(size_t)e0.x * D + lane]);
            const float y1 = __half2float(YH[(size_t)e1.x * D + lane]);
            const float y2 = __half2float(YH[(size_t)e2.x * D + lane]);
            const float y3 = __half2float(YH[(size_t)e3.x * D + lane]);
            const float y4 = __half2float(YH[(size_t)e4.x * D + lane]);
            const float y5 = __half2float(YH[(size_t)e5.x * D + lane]);
            const float y6 = __half2float(YH[(size_t)e6.x * D + lane]);
            const float y7 = __half2float(YH[(size_t)e7.x * D + lane]);
            acc2 = fmaf(__int_as_float(e0.y), y0, acc2);
            acc2 = fmaf(__int_as_float(e1.y), y1, acc2);
            acc2 = fmaf(__int_as_float(e2.y), y2, acc2);
            acc2 = fmaf(__int_as_float(e3.y), y3, acc2);
            acc2 = fmaf(__int_as_float(e4.y), y4, acc2);
            acc2 = fmaf(__int_as_float(e5.y), y5, acc2);
            acc2 = fmaf(__int_as_float(e6.y), y6, acc2);
            acc2 = fmaf(__int_as_float(e7.y), y7, acc2);
        }
        if (j + 4 <= je) {
            const int2 e0 = sbuf[j + 0], e1 = sbuf[j + 1];
            const int2 e2 = sbuf[j + 2], e3 = sbuf[j + 3];
            const float y0 = __half2float(YH[(size_t)e0.x * D + lane]);
            const float y1 = __half2float(YH[(size_t)e1.x * D + lane]);
            const float y2 = __half2float(YH[(size_t)e2.x * D + lane]);
            const float y3 = __half2float(YH[(size_t)e3.x * D + lane]);
            acc2 = fmaf(__int_as_float(e0.y), y0, acc2);
            acc2 = fmaf(__int_as_float(e1.y), y1, acc2);
            acc2 = fmaf(__int_as_float(e2.y), y2, acc2);
            acc2 = fmaf(__int_as_float(e3.y), y3, acc2);
            j += 4;
        }
        for (; j < je; ++j) {
            const int2 e = sbuf[j];
            acc2 = fmaf(__int_as_float(e.y),
                        __half2float(YH[(size_t)e.x * D + lane]), acc2);
        }
        const int grow = rows0 + lr;
        if (grow < NN) out[(size_t)grow * D + lane] = acc2;
    }
}

// ---------- fallback (round-1 proven path) ----------
__global__ __launch_bounds__(256) void gcn_scatter_kernel(
    const int* __restrict__ rows, const int* __restrict__ cols,
    const float* __restrict__ vals, const float* __restrict__ X,
    float* __restrict__ agg)
{
    const int e    = blockIdx.x * 4 + (threadIdx.x >> 6);
    const int lane = threadIdx.x & 63;
    atomicAdd(&agg[rows[e] * D + lane], vals[e] * X[cols[e] * D + lane]);
}

__global__ __launch_bounds__(256) void gcn_transform_kernel(
    const float* __restrict__ W, const float* __restrict__ bias,
    float* __restrict__ out)
{
    __shared__ float Wl[D][D + 1];
    __shared__ float rowbuf[4][D];
    const int tid = threadIdx.x;
    for (int i = tid; i < D * D; i += 256)
        Wl[i >> 6][i & 63] = W[i];
    const int wave = tid >> 6, lane = tid & 63;
    const int n = blockIdx.x * 4 + wave;
    rowbuf[wave][lane] = out[n * D + lane];
    __syncthreads();
    float acc = bias[lane];
#pragma unroll
    for (int f = 0; f < D; ++f)
        acc += rowbuf[wave][f] * Wl[lane][f];
    out[n * D + lane] = acc;
}

extern "C" void kernel_launch(void* const* d_in, const int* in_sizes, int n_in,
                              void* d_out, int out_size, void* d_ws, size_t ws_size,
                              hipStream_t stream) {
    const int*   L_rows = (const int*)d_in[0];
    const int*   L_cols = (const int*)d_in[1];
    const float* L_vals = (const float*)d_in[2];
    const float* X      = (const float*)d_in[3];
    const float* W      = (const float*)d_in[4];
    const float* b      = (const float*)d_in[5];
    float* out = (float*)d_out;

    if (ws_size >= WS_NEED) {
        char* w = (char*)d_ws;
        __half* YH     = (__half*)(w + WS_YH);
        int2*   EA     = (int2*)  (w + WS_EA);
        int*    bcnt   = (int*)   (w + WS_BCNT);
        int*    cstart = (int*)   (w + WS_CST);
        int*    cursor = (int*)   (w + WS_CUR);

        hipMemsetAsync(bcnt, 0, 2048, stream);

        gcn_ybuild<<<NN / 16, 256, 0, stream>>>(X, W, YH);
        gcn_bhist<<<256, 256, 0, stream>>>(L_rows, bcnt);
        gcn_bscan<<<1, 512, 0, stream>>>(bcnt, cstart, cursor);
        gcn_place<<<PL_BLOCKS, 256, 0, stream>>>(L_rows, L_cols, L_vals,
                                                 cursor, EA);
        gcn_bucketagg<<<2 * NB, 512, 0, stream>>>(cstart, EA, YH, b, out);
    } else {
        hipMemsetAsync(out, 0, (size_t)out_size * sizeof(float), stream);
        gcn_scatter_kernel<<<NE / 4, 256, 0, stream>>>(L_rows, L_cols, L_vals, X, out);
        gcn_transform_kernel<<<NN / 4, 256, 0, stream>>>(W, b, out);
    }
}

// Round 9
// 121.371 us; speedup vs baseline: 7.0509x; 1.2003x over previous
//
#include <hip/hip_runtime.h>
#include <hip/hip_fp16.h>

// GCN layer: out = segment_sum(L_vals[:,None] * X[L_cols], L_rows) @ W^T + b
//
// Round-9: ybuild rebuilt on MFMA (r8: VALU ybuild was LDS-broadcast-issue
// bound at 52us -- 16 wave-uniform ds_read_b128 per row deliver 16B/12cyc).
// gcn_ybuild_mfma: one wave per 16x16 Y tile, 2x mfma_f32_16x16x32_f16
// (K=64), operands loaded directly from global as float4 and cvt to f16.
// No LDS. A: row=lane&15, k=(lane>>4)*8+e. B: col=lane&15 (W row), same k.
// C/D: col=lane&15, row=(lane>>4)*4+reg (m89-verified).
// Rest of pipeline proven r7/r8: bhist -> bscan -> place -> bucketagg.
// Fallback to round-1 atomic path if ws_size too small.

constexpr int D  = 64;
constexpr int NN = 100000;   // nodes
constexpr int NE = 1600000;  // edges
constexpr int NB = (NN + 255) / 256;   // 391 buckets of 256 rows

// ws layout (bytes)
constexpr size_t WS_YH   = 0;                    // NN*D halfs = 12.8 MB
constexpr size_t WS_EA   = 12800000;             // NE int2 = 12.8 MB
constexpr size_t WS_BCNT = 25600000;             // NB ints
constexpr size_t WS_CST  = WS_BCNT + 2048;       // NB+1 ints
constexpr size_t WS_CUR  = WS_CST + 2048;        // NB ints
constexpr size_t WS_NEED = WS_CUR + 2048;        // ~25.6 MB

typedef _Float16 half8 __attribute__((ext_vector_type(8)));
typedef float    f32x4 __attribute__((ext_vector_type(4)));

// ---------- 1) Y = X @ W^T -> fp16 via MFMA ----------
// Block = 256 thr = 4 waves; block owns 16 rows (m-tile), wave wv owns
// output cols [wv*16, wv*16+16). 6250 blocks.
__global__ __launch_bounds__(256) void gcn_ybuild_mfma(
    const float* __restrict__ X, const float* __restrict__ W,
    __half* __restrict__ YH)
{
    const int tid = threadIdx.x, wv = tid >> 6, lane = tid & 63;
    const int m0  = blockIdx.x * 16;
    const int o0  = wv * 16;
    const int rc  = lane & 15;      // A row / B col(=W row index o0+rc)
    const int kg  = lane >> 4;      // k-group: k = kg*8 + e

    const float* xp = X + (size_t)(m0 + rc) * D + kg * 8;
    const f32x4 a0lo = *(const f32x4*)(xp + 0);
    const f32x4 a0hi = *(const f32x4*)(xp + 4);
    const f32x4 a1lo = *(const f32x4*)(xp + 32);
    const f32x4 a1hi = *(const f32x4*)(xp + 36);

    const float* wp = W + (size_t)(o0 + rc) * D + kg * 8;
    const f32x4 b0lo = *(const f32x4*)(wp + 0);
    const f32x4 b0hi = *(const f32x4*)(wp + 4);
    const f32x4 b1lo = *(const f32x4*)(wp + 32);
    const f32x4 b1hi = *(const f32x4*)(wp + 36);

    half8 a0, a1, b0, b1;
#pragma unroll
    for (int i = 0; i < 4; ++i) {
        a0[i] = (_Float16)a0lo[i]; a0[i + 4] = (_Float16)a0hi[i];
        a1[i] = (_Float16)a1lo[i]; a1[i + 4] = (_Float16)a1hi[i];
        b0[i] = (_Float16)b0lo[i]; b0[i + 4] = (_Float16)b0hi[i];
        b1[i] = (_Float16)b1lo[i]; b1[i + 4] = (_Float16)b1hi[i];
    }

    f32x4 c = {0.f, 0.f, 0.f, 0.f};
    c = __builtin_amdgcn_mfma_f32_16x16x32_f16(a0, b0, c, 0, 0, 0);
    c = __builtin_amdgcn_mfma_f32_16x16x32_f16(a1, b1, c, 0, 0, 0);

    // D: lane holds Y[m0 + kg*4 + r][o0 + rc], r = 0..3
    __half* yb = YH + (size_t)(m0 + kg * 4) * D + o0 + rc;
#pragma unroll
    for (int r = 0; r < 4; ++r)
        yb[(size_t)r * D] = __float2half(c[r]);
}

// ---------- 2) bucket histogram (LDS-assisted) ----------
__global__ __launch_bounds__(256) void gcn_bhist(
    const int* __restrict__ rows, int* __restrict__ bcnt)
{
    __shared__ int h[NB];
    const int tid = threadIdx.x;
    for (int i = tid; i < NB; i += 256) h[i] = 0;
    __syncthreads();
    for (int e = blockIdx.x * 256 + tid; e < NE; e += 256 * 256)
        atomicAdd(&h[rows[e] >> 8], 1);
    __syncthreads();
    for (int i = tid; i < NB; i += 256)
        if (h[i]) atomicAdd(&bcnt[i], h[i]);
}

// ---------- 3) exclusive scan of NB bucket counts -> cstart, cursor --------
__global__ __launch_bounds__(512) void gcn_bscan(
    const int* __restrict__ bcnt, int* __restrict__ cstart,
    int* __restrict__ cursor)
{
    const int tid = threadIdx.x, lane = tid & 63, wid = tid >> 6;
    const int v = (tid < NB) ? bcnt[tid] : 0;
    int acc = v;
#pragma unroll
    for (int s = 1; s < 64; s <<= 1) {
        const int t = __shfl_up(acc, s);
        if (lane >= s) acc += t;
    }
    __shared__ int wsum[8];
    if (lane == 63) wsum[wid] = acc;
    __syncthreads();
    if (tid == 0) {
        int run = 0;
        for (int k = 0; k < 8; ++k) { const int t = wsum[k]; wsum[k] = run; run += t; }
    }
    __syncthreads();
    acc += wsum[wid];
    const int excl = acc - v;
    if (tid < NB) { cstart[tid] = excl; cursor[tid] = excl; }
    if (tid == NB - 1) cstart[NB] = acc;   // == NE
}

// ---------- 4) counting placement into per-bucket runs (proven r7) --------
constexpr int PL_BLOCKS = 256;
constexpr int PL_EPB    = NE / PL_BLOCKS;   // 6250
__global__ __launch_bounds__(256) void gcn_place(
    const int* __restrict__ rows, const int* __restrict__ cols,
    const float* __restrict__ vals, int* __restrict__ cursor,
    int2* __restrict__ EA)
{
    __shared__ int hist[NB];
    __shared__ int rbase[NB];
    const int tid = threadIdx.x;
    const int base = blockIdx.x * PL_EPB;

    for (int i = tid; i < NB; i += 256) hist[i] = 0;
    __syncthreads();
    for (int i = tid; i < PL_EPB; i += 256)
        atomicAdd(&hist[rows[base + i] >> 8], 1);
    __syncthreads();
    for (int i = tid; i < NB; i += 256) {
        const int c = hist[i];
        rbase[i] = c ? atomicAdd(&cursor[i], c) : 0;
    }
    __syncthreads();
    for (int i = tid; i < NB; i += 256) hist[i] = 0;
    __syncthreads();
    for (int i = tid; i < PL_EPB; i += 256) {
        const int e = base + i;
        const int r = rows[e];
        const int b = r >> 8;
        const int rank = atomicAdd(&hist[b], 1);
        EA[rbase[b] + rank] = make_int2(((r & 255) << 17) | cols[e],
                                        __float_as_int(vals[e]));
    }
}

// ---------- 5) fused in-LDS row-sort + aggregate (half-bucket/block) -------
constexpr int HCAP = 2560;   // half-bucket capacity: mean 2046, +11 sigma
__global__ __launch_bounds__(512) void gcn_bucketagg(
    const int* __restrict__ cstart, const int2* __restrict__ EA,
    const __half* __restrict__ YH, const float* __restrict__ bias,
    float* __restrict__ out)
{
    __shared__ int2 sbuf[HCAP];
    __shared__ int hist[128], start[128], curs[128];
    __shared__ int sw1;
    const int tid = threadIdx.x;
    const int bb = blockIdx.x, b = bb >> 1, half = bb & 1;
    const int s = cstart[b], n = cstart[b + 1] - s;

    if (tid < 128) hist[tid] = 0;
    __syncthreads();

    // pass 1: histogram own half's rows
    for (int i = tid; i < n; i += 512) {
        const int rr = EA[s + i].x >> 17;          // row-in-bucket 0..255
        if ((rr >> 7) == half) atomicAdd(&hist[rr & 127], 1);
    }
    __syncthreads();

    // exclusive scan of hist[128]
    int v = 0, acc = 0;
    if (tid < 128) {
        v = hist[tid];
        acc = v;
        const int lane = tid & 63;
#pragma unroll
        for (int st = 1; st < 64; st <<= 1) {
            const int t = __shfl_up(acc, st);
            if (lane >= st) acc += t;
        }
    }
    if (tid == 63) sw1 = acc;
    __syncthreads();
    if (tid >= 64 && tid < 128) acc += sw1;
    if (tid < 128) {
        start[tid] = acc - v;
        curs[tid]  = acc - v;
    }
    __syncthreads();

    // pass 2: place own half's edges into sbuf (row-sorted)
    for (int i = tid; i < n; i += 512) {
        const int2 E = EA[s + i];
        const int rr = E.x >> 17;
        if ((rr >> 7) == half) {
            const int pos = atomicAdd(&curs[rr & 127], 1);
            if (pos < HCAP) sbuf[pos] = make_int2(E.x & 0x1FFFF, E.y);
        }
    }
    __syncthreads();

    // pass 3: wave-per-row aggregate, 16 rows per wave, unroll-8/4
    const int wv = tid >> 6, lane = tid & 63;
    const float bl = bias[lane];
    const int rows0 = b * 256 + half * 128;
#pragma unroll 1
    for (int k = 0; k < 16; ++k) {
        const int lr = wv * 16 + k;
        const int js = start[lr];
        const int je = js + hist[lr];
        float acc2 = bl;
        int j = js;
        for (; j + 8 <= je; j += 8) {
            const int2 e0 = sbuf[j + 0], e1 = sbuf[j + 1];
            const int2 e2 = sbuf[j + 2], e3 = sbuf[j + 3];
            const int2 e4 = sbuf[j + 4], e5 = sbuf[j + 5];
            const int2 e6 = sbuf[j + 6], e7 = sbuf[j + 7];
            const float y0 = __half2float(YH[(size_t)e0.x * D + lane]);
            const float y1 = __half2float(YH[(size_t)e1.x * D + lane]);
            const float y2 = __half2float(YH[(size_t)e2.x * D + lane]);
            const float y3 = __half2float(YH[(size_t)e3.x * D + lane]);
            const float y4 = __half2float(YH[(size_t)e4.x * D + lane]);
            const float y5 = __half2float(YH[(size_t)e5.x * D + lane]);
            const float y6 = __half2float(YH[(size_t)e6.x * D + lane]);
            const float y7 = __half2float(YH[(size_t)e7.x * D + lane]);
            acc2 = fmaf(__int_as_float(e0.y), y0, acc2);
            acc2 = fmaf(__int_as_float(e1.y), y1, acc2);
            acc2 = fmaf(__int_as_float(e2.y), y2, acc2);
            acc2 = fmaf(__int_as_float(e3.y), y3, acc2);
            acc2 = fmaf(__int_as_float(e4.y), y4, acc2);
            acc2 = fmaf(__int_as_float(e5.y), y5, acc2);
            acc2 = fmaf(__int_as_float(e6.y), y6, acc2);
            acc2 = fmaf(__int_as_float(e7.y), y7, acc2);
        }
        if (j + 4 <= je) {
            const int2 e0 = sbuf[j + 0], e1 = sbuf[j + 1];
            const int2 e2 = sbuf[j + 2], e3 = sbuf[j + 3];
            const float y0 = __half2float(YH[(size_t)e0.x * D + lane]);
            const float y1 = __half2float(YH[(size_t)e1.x * D + lane]);
            const float y2 = __half2float(YH[(size_t)e2.x * D + lane]);
            const float y3 = __half2float(YH[(size_t)e3.x * D + lane]);
            acc2 = fmaf(__int_as_float(e0.y), y0, acc2);
            acc2 = fmaf(__int_as_float(e1.y), y1, acc2);
            acc2 = fmaf(__int_as_float(e2.y), y2, acc2);
            acc2 = fmaf(__int_as_float(e3.y), y3, acc2);
            j += 4;
        }
        for (; j < je; ++j) {
            const int2 e = sbuf[j];
            acc2 = fmaf(__int_as_float(e.y),
                        __half2float(YH[(size_t)e.x * D + lane]), acc2);
        }
        const int grow = rows0 + lr;
        if (grow < NN) out[(size_t)grow * D + lane] = acc2;
    }
}

// ---------- fallback (round-1 proven path) ----------
__global__ __launch_bounds__(256) void gcn_scatter_kernel(
    const int* __restrict__ rows, const int* __restrict__ cols,
    const float* __restrict__ vals, const float* __restrict__ X,
    float* __restrict__ agg)
{
    const int e    = blockIdx.x * 4 + (threadIdx.x >> 6);
    const int lane = threadIdx.x & 63;
    atomicAdd(&agg[rows[e] * D + lane], vals[e] * X[cols[e] * D + lane]);
}

__global__ __launch_bounds__(256) void gcn_transform_kernel(
    const float* __restrict__ W, const float* __restrict__ bias,
    float* __restrict__ out)
{
    __shared__ float Wl[D][D + 1];
    __shared__ float rowbuf[4][D];
    const int tid = threadIdx.x;
    for (int i = tid; i < D * D; i += 256)
        Wl[i >> 6][i & 63] = W[i];
    const int wave = tid >> 6, lane = tid & 63;
    const int n = blockIdx.x * 4 + wave;
    rowbuf[wave][lane] = out[n * D + lane];
    __syncthreads();
    float acc = bias[lane];
#pragma unroll
    for (int f = 0; f < D; ++f)
        acc += rowbuf[wave][f] * Wl[lane][f];
    out[n * D + lane] = acc;
}

extern "C" void kernel_launch(void* const* d_in, const int* in_sizes, int n_in,
                              void* d_out, int out_size, void* d_ws, size_t ws_size,
                              hipStream_t stream) {
    const int*   L_rows = (const int*)d_in[0];
    const int*   L_cols = (const int*)d_in[1];
    const float* L_vals = (const float*)d_in[2];
    const float* X      = (const float*)d_in[3];
    const float* W      = (const float*)d_in[4];
    const float* b      = (const float*)d_in[5];
    float* out = (float*)d_out;

    if (ws_size >= WS_NEED) {
        char* w = (char*)d_ws;
        __half* YH     = (__half*)(w + WS_YH);
        int2*   EA     = (int2*)  (w + WS_EA);
        int*    bcnt   = (int*)   (w + WS_BCNT);
        int*    cstart = (int*)   (w + WS_CST);
        int*    cursor = (int*)   (w + WS_CUR);

        hipMemsetAsync(bcnt, 0, 2048, stream);

        gcn_ybuild_mfma<<<NN / 16, 256, 0, stream>>>(X, W, YH);
        gcn_bhist<<<256, 256, 0, stream>>>(L_rows, bcnt);
        gcn_bscan<<<1, 512, 0, stream>>>(bcnt, cstart, cursor);
        gcn_place<<<PL_BLOCKS, 256, 0, stream>>>(L_rows, L_cols, L_vals,
                                                 cursor, EA);
        gcn_bucketagg<<<2 * NB, 512, 0, stream>>>(cstart, EA, YH, b, out);
    } else {
        hipMemsetAsync(out, 0, (size_t)out_size * sizeof(float), stream);
        gcn_scatter_kernel<<<NE / 4, 256, 0, stream>>>(L_rows, L_cols, L_vals, X, out);
        gcn_transform_kernel<<<NN / 4, 256, 0, stream>>>(W, b, out);
    }
}

// Round 10
// 108.208 us; speedup vs baseline: 7.9086x; 1.1216x over previous
//
#include <hip/hip_runtime.h>
#include <hip/hip_fp16.h>

// GCN layer: out = segment_sum(L_vals[:,None] * X[L_cols], L_rows) @ W^T + b
//
// Round-10: 3-kernel pipeline. r9 analysis: bucketagg at 50% occupancy with
// 3.05 blocks/CU tail; ~35us of small dispatches (bhist/bscan/memset) +
// launch drains. Fix: fixed-capacity sub-bucket EA regions kill the global
// hist+scan; finer aggregate blocks fix tail/occupancy.
//   1) ybuild_mfma: Y = X@W^T -> fp16 via 2x mfma_16x16x32_f16 (proven r9);
//                   block 0 also inits cursor[i] = i*PADQ
//   2) place:       256 blocks; per-block LDS hist over 1563 sub-buckets
//                   (64 rows each) -> one global atomicAdd per non-empty bin
//                   reserves a run in that bin's FIXED region -> direct stores
//   3) subagg:      1563 blocks (one per sub-bucket, 256 thr); in-LDS
//                   row-sort (hist[64] + 1-wave scan + place into sbuf) then
//                   wave-per-row unroll-8 fp16-Y gather aggregate (proven)
// Fallback to round-1 atomic path if ws_size too small.

constexpr int D    = 64;
constexpr int NN   = 100000;   // nodes
constexpr int NE   = 1600000;  // edges
constexpr int SBR  = 64;                      // rows per sub-bucket
constexpr int NSB  = (NN + SBR - 1) / SBR;    // 1563 sub-buckets
constexpr int PADQ = 1280;                    // region capacity (mean 1024 + 8σ)

// ws layout (bytes)
constexpr size_t WS_YH   = 0;                         // NN*D halfs = 12.8 MB
constexpr size_t WS_EA   = 12800000;                  // NSB*PADQ int2 = 16.0 MB
constexpr size_t WS_CUR  = WS_EA + 8ull * NSB * PADQ; // NSB ints
constexpr size_t WS_NEED = WS_CUR + 8192;             // ~28.8 MB

typedef _Float16 half8 __attribute__((ext_vector_type(8)));
typedef float    f32x4 __attribute__((ext_vector_type(4)));

// ---------- 1) Y = X @ W^T -> fp16 via MFMA (proven r9) + cursor init ------
__global__ __launch_bounds__(256) void gcn_ybuild_mfma(
    const float* __restrict__ X, const float* __restrict__ W,
    __half* __restrict__ YH, int* __restrict__ cursor)
{
    const int tid = threadIdx.x, wv = tid >> 6, lane = tid & 63;

    if (blockIdx.x == 0)
        for (int i = tid; i < NSB; i += 256) cursor[i] = i * PADQ;

    const int m0  = blockIdx.x * 16;
    const int o0  = wv * 16;
    const int rc  = lane & 15;      // A row / B col (W row o0+rc)
    const int kg  = lane >> 4;      // k-group: k = kg*8 + e

    const float* xp = X + (size_t)(m0 + rc) * D + kg * 8;
    const f32x4 a0lo = *(const f32x4*)(xp + 0);
    const f32x4 a0hi = *(const f32x4*)(xp + 4);
    const f32x4 a1lo = *(const f32x4*)(xp + 32);
    const f32x4 a1hi = *(const f32x4*)(xp + 36);

    const float* wp = W + (size_t)(o0 + rc) * D + kg * 8;
    const f32x4 b0lo = *(const f32x4*)(wp + 0);
    const f32x4 b0hi = *(const f32x4*)(wp + 4);
    const f32x4 b1lo = *(const f32x4*)(wp + 32);
    const f32x4 b1hi = *(const f32x4*)(wp + 36);

    half8 a0, a1, b0, b1;
#pragma unroll
    for (int i = 0; i < 4; ++i) {
        a0[i] = (_Float16)a0lo[i]; a0[i + 4] = (_Float16)a0hi[i];
        a1[i] = (_Float16)a1lo[i]; a1[i + 4] = (_Float16)a1hi[i];
        b0[i] = (_Float16)b0lo[i]; b0[i + 4] = (_Float16)b0hi[i];
        b1[i] = (_Float16)b1lo[i]; b1[i + 4] = (_Float16)b1hi[i];
    }

    f32x4 c = {0.f, 0.f, 0.f, 0.f};
    c = __builtin_amdgcn_mfma_f32_16x16x32_f16(a0, b0, c, 0, 0, 0);
    c = __builtin_amdgcn_mfma_f32_16x16x32_f16(a1, b1, c, 0, 0, 0);

    __half* yb = YH + (size_t)(m0 + kg * 4) * D + o0 + rc;
#pragma unroll
    for (int r = 0; r < 4; ++r)
        yb[(size_t)r * D] = __float2half(c[r]);
}

// ---------- 2) counting placement into fixed sub-bucket regions ----------
constexpr int PL_BLOCKS = 256;
constexpr int PL_EPB    = NE / PL_BLOCKS;   // 6250
__global__ __launch_bounds__(256) void gcn_place(
    const int* __restrict__ rows, const int* __restrict__ cols,
    const float* __restrict__ vals, int* __restrict__ cursor,
    int2* __restrict__ EA)
{
    __shared__ int hist[NSB];    // pass1: counts; pass2: local rank cursor
    __shared__ int rbase[NSB];   // reserved global run start per bin
    const int tid = threadIdx.x;
    const int base = blockIdx.x * PL_EPB;

    for (int i = tid; i < NSB; i += 256) hist[i] = 0;
    __syncthreads();
    for (int i = tid; i < PL_EPB; i += 256)
        atomicAdd(&hist[rows[base + i] >> 6], 1);
    __syncthreads();
    for (int i = tid; i < NSB; i += 256) {
        const int c = hist[i];
        rbase[i] = c ? atomicAdd(&cursor[i], c) : 0;
    }
    __syncthreads();
    for (int i = tid; i < NSB; i += 256) hist[i] = 0;
    __syncthreads();
    for (int i = tid; i < PL_EPB; i += 256) {
        const int e = base + i;
        const int r = rows[e];              // L2-hot re-read
        const int b = r >> 6;
        const int rank = atomicAdd(&hist[b], 1);
        const int pos = rbase[b] + rank;
        if (pos < (b + 1) * PADQ)           // region-overflow guard (8σ: never)
            EA[pos] = make_int2(((r & 63) << 17) | cols[e],
                                __float_as_int(vals[e]));
    }
}

// ---------- 3) per-sub-bucket in-LDS row-sort + aggregate ----------
__global__ __launch_bounds__(256) void gcn_subagg(
    const int* __restrict__ cursor, const int2* __restrict__ EA,
    const __half* __restrict__ YH, const float* __restrict__ bias,
    float* __restrict__ out)
{
    __shared__ int2 sbuf[PADQ];
    __shared__ int hist[SBR], start[SBR], curs[SBR];
    const int tid = threadIdx.x;
    const int sb  = blockIdx.x;
    const int s   = sb * PADQ;
    const int n   = min(cursor[sb] - s, PADQ);

    if (tid < SBR) hist[tid] = 0;
    __syncthreads();

    // pass 1: histogram rows (6-bit row-in-sub-bucket)
    for (int i = tid; i < n; i += 256)
        atomicAdd(&hist[EA[s + i].x >> 17], 1);
    __syncthreads();

    // single-wave exclusive scan of hist[64]
    if (tid < SBR) {
        const int v = hist[tid];
        int acc = v;
#pragma unroll
        for (int st = 1; st < 64; st <<= 1) {
            const int t = __shfl_up(acc, st);
            if (tid >= st) acc += t;
        }
        start[tid] = acc - v;
        curs[tid]  = acc - v;
    }
    __syncthreads();

    // pass 2: place into sbuf (row-sorted)
    for (int i = tid; i < n; i += 256) {
        const int2 E = EA[s + i];
        const int pos = atomicAdd(&curs[E.x >> 17], 1);
        if (pos < PADQ) sbuf[pos] = make_int2(E.x & 0x1FFFF, E.y);
    }
    __syncthreads();

    // pass 3: wave-per-row aggregate, 16 rows per wave, unroll-8/4
    const int wv = tid >> 6, lane = tid & 63;
    const float bl = bias[lane];
    const int rows0 = sb * SBR;
#pragma unroll 1
    for (int k = 0; k < 16; ++k) {
        const int lr = wv * 16 + k;
        const int js = start[lr];
        const int je = js + hist[lr];
        float acc2 = bl;
        int j = js;
        for (; j + 8 <= je; j += 8) {
            const int2 e0 = sbuf[j + 0], e1 = sbuf[j + 1];
            const int2 e2 = sbuf[j + 2], e3 = sbuf[j + 3];
            const int2 e4 = sbuf[j + 4], e5 = sbuf[j + 5];
            const int2 e6 = sbuf[j + 6], e7 = sbuf[j + 7];
            const float y0 = __half2float(YH[(size_t)e0.x * D + lane]);
            const float y1 = __half2float(YH[(size_t)e1.x * D + lane]);
            const float y2 = __half2float(YH[(size_t)e2.x * D + lane]);
            const float y3 = __half2float(YH[(size_t)e3.x * D + lane]);
            const float y4 = __half2float(YH[(size_t)e4.x * D + lane]);
            const float y5 = __half2float(YH[(size_t)e5.x * D + lane]);
            const float y6 = __half2float(YH[(size_t)e6.x * D + lane]);
            const float y7 = __half2float(YH[(size_t)e7.x * D + lane]);
            acc2 = fmaf(__int_as_float(e0.y), y0, acc2);
            acc2 = fmaf(__int_as_float(e1.y), y1, acc2);
            acc2 = fmaf(__int_as_float(e2.y), y2, acc2);
            acc2 = fmaf(__int_as_float(e3.y), y3, acc2);
            acc2 = fmaf(__int_as_float(e4.y), y4, acc2);
            acc2 = fmaf(__int_as_float(e5.y), y5, acc2);
            acc2 = fmaf(__int_as_float(e6.y), y6, acc2);
            acc2 = fmaf(__int_as_float(e7.y), y7, acc2);
        }
        if (j + 4 <= je) {
            const int2 e0 = sbuf[j + 0], e1 = sbuf[j + 1];
            const int2 e2 = sbuf[j + 2], e3 = sbuf[j + 3];
            const float y0 = __half2float(YH[(size_t)e0.x * D + lane]);
            const float y1 = __half2float(YH[(size_t)e1.x * D + lane]);
            const float y2 = __half2float(YH[(size_t)e2.x * D + lane]);
            const float y3 = __half2float(YH[(size_t)e3.x * D + lane]);
            acc2 = fmaf(__int_as_float(e0.y), y0, acc2);
            acc2 = fmaf(__int_as_float(e1.y), y1, acc2);
            acc2 = fmaf(__int_as_float(e2.y), y2, acc2);
            acc2 = fmaf(__int_as_float(e3.y), y3, acc2);
            j += 4;
        }
        for (; j < je; ++j) {
            const int2 e = sbuf[j];
            acc2 = fmaf(__int_as_float(e.y),
                        __half2float(YH[(size_t)e.x * D + lane]), acc2);
        }
        const int grow = rows0 + lr;
        if (grow < NN) out[(size_t)grow * D + lane] = acc2;
    }
}

// ---------- fallback (round-1 proven path) ----------
__global__ __launch_bounds__(256) void gcn_scatter_kernel(
    const int* __restrict__ rows, const int* __restrict__ cols,
    const float* __restrict__ vals, const float* __restrict__ X,
    float* __restrict__ agg)
{
    const int e    = blockIdx.x * 4 + (threadIdx.x >> 6);
    const int lane = threadIdx.x & 63;
    atomicAdd(&agg[rows[e] * D + lane], vals[e] * X[cols[e] * D + lane]);
}

__global__ __launch_bounds__(256) void gcn_transform_kernel(
    const float* __restrict__ W, const float* __restrict__ bias,
    float* __restrict__ out)
{
    __shared__ float Wl[D][D + 1];
    __shared__ float rowbuf[4][D];
    const int tid = threadIdx.x;
    for (int i = tid; i < D * D; i += 256)
        Wl[i >> 6][i & 63] = W[i];
    const int wave = tid >> 6, lane = tid & 63;
    const int n = blockIdx.x * 4 + wave;
    rowbuf[wave][lane] = out[n * D + lane];
    __syncthreads();
    float acc = bias[lane];
#pragma unroll
    for (int f = 0; f < D; ++f)
        acc += rowbuf[wave][f] * Wl[lane][f];
    out[n * D + lane] = acc;
}

extern "C" void kernel_launch(void* const* d_in, const int* in_sizes, int n_in,
                              void* d_out, int out_size, void* d_ws, size_t ws_size,
                              hipStream_t stream) {
    const int*   L_rows = (const int*)d_in[0];
    const int*   L_cols = (const int*)d_in[1];
    const float* L_vals = (const float*)d_in[2];
    const float* X      = (const float*)d_in[3];
    const float* W      = (const float*)d_in[4];
    const float* b      = (const float*)d_in[5];
    float* out = (float*)d_out;

    if (ws_size >= WS_NEED) {
        char* w = (char*)d_ws;
        __half* YH     = (__half*)(w + WS_YH);
        int2*   EA     = (int2*)  (w + WS_EA);
        int*    cursor = (int*)   (w + WS_CUR);

        gcn_ybuild_mfma<<<NN / 16, 256, 0, stream>>>(X, W, YH, cursor);
        gcn_place<<<PL_BLOCKS, 256, 0, stream>>>(L_rows, L_cols, L_vals,
                                                 cursor, EA);
        gcn_subagg<<<NSB, 256, 0, stream>>>(cursor, EA, YH, b, out);
    } else {
        hipMemsetAsync(out, 0, (size_t)out_size * sizeof(float), stream);
        gcn_scatter_kernel<<<NE / 4, 256, 0, stream>>>(L_rows, L_cols, L_vals, X, out);
        gcn_transform_kernel<<<NN / 4, 256, 0, stream>>>(W, b, out);
    }
}

// Round 11
// 99.046 us; speedup vs baseline: 8.6402x; 1.0925x over previous
//
#include <hip/hip_runtime.h>
#include <hip/hip_fp16.h>

// GCN layer: out = segment_sum(L_vals[:,None] * X[L_cols], L_rows) @ W^T + b
//
// Round-11: place was latency-bound at 1 block/CU (256 blocks x 256 thr =
// 4 waves/CU, Occ 9.35%, VALU 1.6%). Same algorithm, 1024 thr/block ->
// 16 waves/CU, 4x latency hiding. Everything else proven r10:
//   1) ybuild_mfma: Y = X@W^T -> fp16 via 2x mfma_16x16x32_f16 (+cursor init)
//   2) place:       256 blocks x 1024 thr; LDS hist over 1563 sub-buckets ->
//                   one global atomicAdd per non-empty bin reserves a run in
//                   the bin's FIXED region (PADQ=1280) -> direct stores
//   3) subagg:      1563 blocks x 256 thr; in-LDS row-sort + wave-per-row
//                   unroll-8 fp16-Y gather aggregate
// Fallback to round-1 atomic path if ws_size too small.

constexpr int D    = 64;
constexpr int NN   = 100000;   // nodes
constexpr int NE   = 1600000;  // edges
constexpr int SBR  = 64;                      // rows per sub-bucket
constexpr int NSB  = (NN + SBR - 1) / SBR;    // 1563 sub-buckets
constexpr int PADQ = 1280;                    // region capacity (mean 1024 + 8σ)

// ws layout (bytes)
constexpr size_t WS_YH   = 0;                         // NN*D halfs = 12.8 MB
constexpr size_t WS_EA   = 12800000;                  // NSB*PADQ int2 = 16.0 MB
constexpr size_t WS_CUR  = WS_EA + 8ull * NSB * PADQ; // NSB ints
constexpr size_t WS_NEED = WS_CUR + 8192;             // ~28.8 MB

typedef _Float16 half8 __attribute__((ext_vector_type(8)));
typedef float    f32x4 __attribute__((ext_vector_type(4)));

// ---------- 1) Y = X @ W^T -> fp16 via MFMA (proven r9) + cursor init ------
__global__ __launch_bounds__(256) void gcn_ybuild_mfma(
    const float* __restrict__ X, const float* __restrict__ W,
    __half* __restrict__ YH, int* __restrict__ cursor)
{
    const int tid = threadIdx.x, wv = tid >> 6, lane = tid & 63;

    if (blockIdx.x == 0)
        for (int i = tid; i < NSB; i += 256) cursor[i] = i * PADQ;

    const int m0  = blockIdx.x * 16;
    const int o0  = wv * 16;
    const int rc  = lane & 15;      // A row / B col (W row o0+rc)
    const int kg  = lane >> 4;      // k-group: k = kg*8 + e

    const float* xp = X + (size_t)(m0 + rc) * D + kg * 8;
    const f32x4 a0lo = *(const f32x4*)(xp + 0);
    const f32x4 a0hi = *(const f32x4*)(xp + 4);
    const f32x4 a1lo = *(const f32x4*)(xp + 32);
    const f32x4 a1hi = *(const f32x4*)(xp + 36);

    const float* wp = W + (size_t)(o0 + rc) * D + kg * 8;
    const f32x4 b0lo = *(const f32x4*)(wp + 0);
    const f32x4 b0hi = *(const f32x4*)(wp + 4);
    const f32x4 b1lo = *(const f32x4*)(wp + 32);
    const f32x4 b1hi = *(const f32x4*)(wp + 36);

    half8 a0, a1, b0, b1;
#pragma unroll
    for (int i = 0; i < 4; ++i) {
        a0[i] = (_Float16)a0lo[i]; a0[i + 4] = (_Float16)a0hi[i];
        a1[i] = (_Float16)a1lo[i]; a1[i + 4] = (_Float16)a1hi[i];
        b0[i] = (_Float16)b0lo[i]; b0[i + 4] = (_Float16)b0hi[i];
        b1[i] = (_Float16)b1lo[i]; b1[i + 4] = (_Float16)b1hi[i];
    }

    f32x4 c = {0.f, 0.f, 0.f, 0.f};
    c = __builtin_amdgcn_mfma_f32_16x16x32_f16(a0, b0, c, 0, 0, 0);
    c = __builtin_amdgcn_mfma_f32_16x16x32_f16(a1, b1, c, 0, 0, 0);

    __half* yb = YH + (size_t)(m0 + kg * 4) * D + o0 + rc;
#pragma unroll
    for (int r = 0; r < 4; ++r)
        yb[(size_t)r * D] = __float2half(c[r]);
}

// ---------- 2) counting placement into fixed sub-bucket regions ----------
// 256 blocks x 1024 thr (16 waves/CU): r10's 256-thr version was
// latency-bound at 4 waves/CU.
constexpr int PL_BLOCKS = 256;
constexpr int PL_EPB    = NE / PL_BLOCKS;   // 6250
__global__ __launch_bounds__(1024) void gcn_place(
    const int* __restrict__ rows, const int* __restrict__ cols,
    const float* __restrict__ vals, int* __restrict__ cursor,
    int2* __restrict__ EA)
{
    __shared__ int hist[NSB];    // pass1: counts; pass2: local rank cursor
    __shared__ int rbase[NSB];   // reserved global run start per bin
    const int tid = threadIdx.x;
    const int base = blockIdx.x * PL_EPB;

    for (int i = tid; i < NSB; i += 1024) hist[i] = 0;
    __syncthreads();
    for (int i = tid; i < PL_EPB; i += 1024)
        atomicAdd(&hist[rows[base + i] >> 6], 1);
    __syncthreads();
    for (int i = tid; i < NSB; i += 1024) {
        const int c = hist[i];
        rbase[i] = c ? atomicAdd(&cursor[i], c) : 0;
    }
    __syncthreads();
    for (int i = tid; i < NSB; i += 1024) hist[i] = 0;
    __syncthreads();
    for (int i = tid; i < PL_EPB; i += 1024) {
        const int e = base + i;
        const int r = rows[e];              // L2-hot re-read
        const int b = r >> 6;
        const int rank = atomicAdd(&hist[b], 1);
        const int pos = rbase[b] + rank;
        if (pos < (b + 1) * PADQ)           // region-overflow guard (8σ: never)
            EA[pos] = make_int2(((r & 63) << 17) | cols[e],
                                __float_as_int(vals[e]));
    }
}

// ---------- 3) per-sub-bucket in-LDS row-sort + aggregate ----------
__global__ __launch_bounds__(256) void gcn_subagg(
    const int* __restrict__ cursor, const int2* __restrict__ EA,
    const __half* __restrict__ YH, const float* __restrict__ bias,
    float* __restrict__ out)
{
    __shared__ int2 sbuf[PADQ];
    __shared__ int hist[SBR], start[SBR], curs[SBR];
    const int tid = threadIdx.x;
    const int sb  = blockIdx.x;
    const int s   = sb * PADQ;
    const int n   = min(cursor[sb] - s, PADQ);

    if (tid < SBR) hist[tid] = 0;
    __syncthreads();

    // pass 1: histogram rows (6-bit row-in-sub-bucket)
    for (int i = tid; i < n; i += 256)
        atomicAdd(&hist[EA[s + i].x >> 17], 1);
    __syncthreads();

    // single-wave exclusive scan of hist[64]
    if (tid < SBR) {
        const int v = hist[tid];
        int acc = v;
#pragma unroll
        for (int st = 1; st < 64; st <<= 1) {
            const int t = __shfl_up(acc, st);
            if (tid >= st) acc += t;
        }
        start[tid] = acc - v;
        curs[tid]  = acc - v;
    }
    __syncthreads();

    // pass 2: place into sbuf (row-sorted)
    for (int i = tid; i < n; i += 256) {
        const int2 E = EA[s + i];
        const int pos = atomicAdd(&curs[E.x >> 17], 1);
        if (pos < PADQ) sbuf[pos] = make_int2(E.x & 0x1FFFF, E.y);
    }
    __syncthreads();

    // pass 3: wave-per-row aggregate, 16 rows per wave, unroll-8/4
    const int wv = tid >> 6, lane = tid & 63;
    const float bl = bias[lane];
    const int rows0 = sb * SBR;
#pragma unroll 1
    for (int k = 0; k < 16; ++k) {
        const int lr = wv * 16 + k;
        const int js = start[lr];
        const int je = js + hist[lr];
        float acc2 = bl;
        int j = js;
        for (; j + 8 <= je; j += 8) {
            const int2 e0 = sbuf[j + 0], e1 = sbuf[j + 1];
            const int2 e2 = sbuf[j + 2], e3 = sbuf[j + 3];
            const int2 e4 = sbuf[j + 4], e5 = sbuf[j + 5];
            const int2 e6 = sbuf[j + 6], e7 = sbuf[j + 7];
            const float y0 = __half2float(YH[(size_t)e0.x * D + lane]);
            const float y1 = __half2float(YH[(size_t)e1.x * D + lane]);
            const float y2 = __half2float(YH[(size_t)e2.x * D + lane]);
            const float y3 = __half2float(YH[(size_t)e3.x * D + lane]);
            const float y4 = __half2float(YH[(size_t)e4.x * D + lane]);
            const float y5 = __half2float(YH[(size_t)e5.x * D + lane]);
            const float y6 = __half2float(YH[(size_t)e6.x * D + lane]);
            const float y7 = __half2float(YH[(size_t)e7.x * D + lane]);
            acc2 = fmaf(__int_as_float(e0.y), y0, acc2);
            acc2 = fmaf(__int_as_float(e1.y), y1, acc2);
            acc2 = fmaf(__int_as_float(e2.y), y2, acc2);
            acc2 = fmaf(__int_as_float(e3.y), y3, acc2);
            acc2 = fmaf(__int_as_float(e4.y), y4, acc2);
            acc2 = fmaf(__int_as_float(e5.y), y5, acc2);
            acc2 = fmaf(__int_as_float(e6.y), y6, acc2);
            acc2 = fmaf(__int_as_float(e7.y), y7, acc2);
        }
        if (j + 4 <= je) {
            const int2 e0 = sbuf[j + 0], e1 = sbuf[j + 1];
            const int2 e2 = sbuf[j + 2], e3 = sbuf[j + 3];
            const float y0 = __half2float(YH[(size_t)e0.x * D + lane]);
            const float y1 = __half2float(YH[(size_t)e1.x * D + lane]);
            const float y2 = __half2float(YH[(size_t)e2.x * D + lane]);
            const float y3 = __half2float(YH[(size_t)e3.x * D + lane]);
            acc2 = fmaf(__int_as_float(e0.y), y0, acc2);
            acc2 = fmaf(__int_as_float(e1.y), y1, acc2);
            acc2 = fmaf(__int_as_float(e2.y), y2, acc2);
            acc2 = fmaf(__int_as_float(e3.y), y3, acc2);
            j += 4;
        }
        for (; j < je; ++j) {
            const int2 e = sbuf[j];
            acc2 = fmaf(__int_as_float(e.y),
                        __half2float(YH[(size_t)e.x * D + lane]), acc2);
        }
        const int grow = rows0 + lr;
        if (grow < NN) out[(size_t)grow * D + lane] = acc2;
    }
}

// ---------- fallback (round-1 proven path) ----------
__global__ __launch_bounds__(256) void gcn_scatter_kernel(
    const int* __restrict__ rows, const int* __restrict__ cols,
    const float* __restrict__ vals, const float* __restrict__ X,
    float* __restrict__ agg)
{
    const int e    = blockIdx.x * 4 + (threadIdx.x >> 6);
    const int lane = threadIdx.x & 63;
    atomicAdd(&agg[rows[e] * D + lane], vals[e] * X[cols[e] * D + lane]);
}

__global__ __launch_bounds__(256) void gcn_transform_kernel(
    const float* __restrict__ W, const float* __restrict__ bias,
    float* __restrict__ out)
{
    __shared__ float Wl[D][D + 1];
    __shared__ float rowbuf[4][D];
    const int tid = threadIdx.x;
    for (int i = tid; i < D * D; i += 256)
        Wl[i >> 6][i & 63] = W[i];
    const int wave = tid >> 6, lane = tid & 63;
    const int n = blockIdx.x * 4 + wave;
    rowbuf[wave][lane] = out[n * D + lane];
    __syncthreads();
    float acc = bias[lane];
#pragma unroll
    for (int f = 0; f < D; ++f)
        acc += rowbuf[wave][f] * Wl[lane][f];
    out[n * D + lane] = acc;
}

extern "C" void kernel_launch(void* const* d_in, const int* in_sizes, int n_in,
                              void* d_out, int out_size, void* d_ws, size_t ws_size,
                              hipStream_t stream) {
    const int*   L_rows = (const int*)d_in[0];
    const int*   L_cols = (const int*)d_in[1];
    const float* L_vals = (const float*)d_in[2];
    const float* X      = (const float*)d_in[3];
    const float* W      = (const float*)d_in[4];
    const float* b      = (const float*)d_in[5];
    float* out = (float*)d_out;

    if (ws_size >= WS_NEED) {
        char* w = (char*)d_ws;
        __half* YH     = (__half*)(w + WS_YH);
        int2*   EA     = (int2*)  (w + WS_EA);
        int*    cursor = (int*)   (w + WS_CUR);

        gcn_ybuild_mfma<<<NN / 16, 256, 0, stream>>>(X, W, YH, cursor);
        gcn_place<<<PL_BLOCKS, 1024, 0, stream>>>(L_rows, L_cols, L_vals,
                                                  cursor, EA);
        gcn_subagg<<<NSB, 256, 0, stream>>>(cursor, EA, YH, b, out);
    } else {
        hipMemsetAsync(out, 0, (size_t)out_size * sizeof(float), stream);
        gcn_scatter_kernel<<<NE / 4, 256, 0, stream>>>(L_rows, L_cols, L_vals, X, out);
        gcn_transform_kernel<<<NN / 4, 256, 0, stream>>>(W, b, out);
    }
}